// Round 3
// baseline (311.278 us; speedup 1.0000x reference)
//
#include <hip/hip_runtime.h>
#include <hip/hip_bf16.h>
#include <math.h>

#define BATCH 512

// ---------------- Layer 1: conv 3->16 (3x3 SAME, 64x64) + bn + relu + maxpool2 -> 16x32x32
// grid 1024: (b, half). LDS-padded half-image tile [3][34][66].
__global__ __launch_bounds__(256) void k_conv1(const float* __restrict__ x,
    const float* __restrict__ w, const float* __restrict__ cb,
    const float* __restrict__ g, const float* __restrict__ beta,
    const float* __restrict__ m, const float* __restrict__ v,
    float* __restrict__ out)
{
    __shared__ float tile[3 * 34 * 66];   // 6732 floats = 26.3 KB
    int bid = blockIdx.x;
    int b = bid >> 1, half = bid & 1;
    const float* img = x + (size_t)b * 3 * 4096;
    int y0 = 32 * half - 1;
    for (int idx = threadIdx.x; idx < 6732; idx += 256) {
        int ic = idx / 2244, rem = idx % 2244;
        int yy = rem / 66, xxp = rem % 66;
        int y = y0 + yy, xx = xxp - 1;
        float val = 0.f;
        if ((unsigned)y < 64u && (unsigned)xx < 64u) val = img[ic * 4096 + y * 64 + xx];
        tile[idx] = val;
    }
    __syncthreads();
    #pragma unroll 1
    for (int it = 0; it < 2; ++it) {
        int pos = threadIdx.x + it * 256;          // 512 pooled positions per block
        int pw = pos & 31, phl = pos >> 5;         // phl 0..15
        float p[3][4][4];
        #pragma unroll
        for (int ic = 0; ic < 3; ++ic)
            #pragma unroll
            for (int dy = 0; dy < 4; ++dy)
                #pragma unroll
                for (int dx = 0; dx < 4; ++dx)
                    p[ic][dy][dx] = tile[ic * 2244 + (2 * phl + dy) * 66 + 2 * pw + dx];
        float* op = out + (size_t)b * 16384 + (half * 16 + phl) * 32 + pw;
        #pragma unroll
        for (int oc = 0; oc < 16; ++oc) {
            float inv = g[oc] * rsqrtf(v[oc] + 1e-5f);
            float bs  = (cb[oc] - m[oc]) * inv + beta[oc];
            float a0 = 0.f, a1 = 0.f, a2 = 0.f, a3 = 0.f;
            #pragma unroll
            for (int ic = 0; ic < 3; ++ic)
                #pragma unroll
                for (int ky = 0; ky < 3; ++ky)
                    #pragma unroll
                    for (int kx = 0; kx < 3; ++kx) {
                        float wv = w[((oc * 3 + ic) * 3 + ky) * 3 + kx];
                        a0 = fmaf(p[ic][ky][kx],         wv, a0);
                        a1 = fmaf(p[ic][ky][kx + 1],     wv, a1);
                        a2 = fmaf(p[ic][ky + 1][kx],     wv, a2);
                        a3 = fmaf(p[ic][ky + 1][kx + 1], wv, a3);
                    }
            float r = fmaxf(fmaxf(fmaxf(a0 * inv + bs, 0.f), fmaxf(a1 * inv + bs, 0.f)),
                            fmaxf(fmaxf(a2 * inv + bs, 0.f), fmaxf(a3 * inv + bs, 0.f)));
            op[oc * 1024] = r;
        }
    }
}

// ---------------- Layer 2: conv 16->32 (3x3 SAME, 32x32) + bn + relu + maxpool2 -> 32x16x16
// grid 2048: (b, ocg of 8 oc) -> acc[8][4] = 32 VGPRs, no spill.
// LDS-padded tile [8 ic][34][34], 2 ic-chunks.
__global__ __launch_bounds__(256) void k_conv2(const float* __restrict__ in,
    const float* __restrict__ w, const float* __restrict__ cb,
    const float* __restrict__ g, const float* __restrict__ beta,
    const float* __restrict__ m, const float* __restrict__ v,
    float* __restrict__ out)
{
    __shared__ float tile[8 * 34 * 34];   // 9248 floats = 37 KB
    int bid = blockIdx.x;
    int b = bid >> 2, ocg = bid & 3;      // 8 oc per block
    const float* src = in + (size_t)b * 16384;
    int t = threadIdx.x;
    int pw = t & 15, ph = t >> 4;
    float acc[8][4];
    #pragma unroll
    for (int o = 0; o < 8; ++o)
        #pragma unroll
        for (int j = 0; j < 4; ++j) acc[o][j] = 0.f;
    #pragma unroll 1
    for (int c = 0; c < 2; ++c) {
        if (c) __syncthreads();
        for (int idx = t; idx < 9248; idx += 256) {
            int icc = idx / 1156, rem = idx % 1156;
            int yy = rem / 34, xxp = rem % 34;
            int y = yy - 1, xx = xxp - 1;
            float val = 0.f;
            if ((unsigned)y < 32u && (unsigned)xx < 32u) val = src[(c * 8 + icc) * 1024 + y * 32 + xx];
            tile[idx] = val;
        }
        __syncthreads();
        #pragma unroll 1
        for (int icc = 0; icc < 8; ++icc) {
            float p[4][4];
            #pragma unroll
            for (int dy = 0; dy < 4; ++dy)
                #pragma unroll
                for (int dx = 0; dx < 4; ++dx)
                    p[dy][dx] = tile[icc * 1156 + (2 * ph + dy) * 34 + 2 * pw + dx];
            int ic = c * 8 + icc;
            #pragma unroll
            for (int o = 0; o < 8; ++o) {
                int oc = ocg * 8 + o;
                const float* wp = w + (oc * 16 + ic) * 9;
                #pragma unroll
                for (int ky = 0; ky < 3; ++ky)
                    #pragma unroll
                    for (int kx = 0; kx < 3; ++kx) {
                        float wv = wp[ky * 3 + kx];
                        acc[o][0] = fmaf(p[ky][kx],         wv, acc[o][0]);
                        acc[o][1] = fmaf(p[ky][kx + 1],     wv, acc[o][1]);
                        acc[o][2] = fmaf(p[ky + 1][kx],     wv, acc[o][2]);
                        acc[o][3] = fmaf(p[ky + 1][kx + 1], wv, acc[o][3]);
                    }
            }
        }
    }
    #pragma unroll
    for (int o = 0; o < 8; ++o) {
        int oc = ocg * 8 + o;
        float inv = g[oc] * rsqrtf(v[oc] + 1e-5f);
        float bs  = (cb[oc] - m[oc]) * inv + beta[oc];
        float r = fmaxf(fmaxf(fmaxf(acc[o][0] * inv + bs, 0.f), fmaxf(acc[o][1] * inv + bs, 0.f)),
                        fmaxf(fmaxf(acc[o][2] * inv + bs, 0.f), fmaxf(acc[o][3] * inv + bs, 0.f)));
        out[(((size_t)b * 32 + oc) << 8) + (ph << 4) + pw] = r;
    }
}

// ---------------- Layer 3: conv 32->64 (3x3 SAME, 16x16) + bn + relu + maxpool2 -> 64x8x8
// grid 1024: (b, half of 32 oc). 256 threads = 64 pos x 4 og (8 oc each).
// LDS-padded tile [16 ic][18][18], 2 ic-chunks.
__global__ __launch_bounds__(256) void k_conv3(const float* __restrict__ in,
    const float* __restrict__ w, const float* __restrict__ cb,
    const float* __restrict__ g, const float* __restrict__ beta,
    const float* __restrict__ m, const float* __restrict__ v,
    float* __restrict__ out)
{
    __shared__ float tile[16 * 18 * 18];  // 5184 floats = 20.25 KB
    int bid = blockIdx.x;
    int b = bid >> 1, half = bid & 1;
    int t = threadIdx.x;
    int og = __builtin_amdgcn_readfirstlane(t >> 6);   // wave-uniform -> scalar weight loads
    int pos = t & 63, pw = pos & 7, ph = pos >> 3;
    int ocbase = half * 32 + og * 8;
    const float* src = in + (size_t)b * 8192;
    float acc[8][4];
    #pragma unroll
    for (int o = 0; o < 8; ++o)
        #pragma unroll
        for (int j = 0; j < 4; ++j) acc[o][j] = 0.f;
    #pragma unroll 1
    for (int c = 0; c < 2; ++c) {
        if (c) __syncthreads();
        for (int idx = t; idx < 5184; idx += 256) {
            int icc = idx / 324, rem = idx % 324;
            int yy = rem / 18, xxp = rem % 18;
            int y = yy - 1, xx = xxp - 1;
            float val = 0.f;
            if ((unsigned)y < 16u && (unsigned)xx < 16u) val = src[(c * 16 + icc) * 256 + y * 16 + xx];
            tile[idx] = val;
        }
        __syncthreads();
        #pragma unroll 1
        for (int icc = 0; icc < 16; ++icc) {
            float p[4][4];
            #pragma unroll
            for (int dy = 0; dy < 4; ++dy)
                #pragma unroll
                for (int dx = 0; dx < 4; ++dx)
                    p[dy][dx] = tile[icc * 324 + (2 * ph + dy) * 18 + 2 * pw + dx];
            int ic = c * 16 + icc;
            #pragma unroll
            for (int o = 0; o < 8; ++o) {
                int oc = ocbase + o;
                const float* wp = w + (oc * 32 + ic) * 9;
                #pragma unroll
                for (int ky = 0; ky < 3; ++ky)
                    #pragma unroll
                    for (int kx = 0; kx < 3; ++kx) {
                        float wv = wp[ky * 3 + kx];
                        acc[o][0] = fmaf(p[ky][kx],         wv, acc[o][0]);
                        acc[o][1] = fmaf(p[ky][kx + 1],     wv, acc[o][1]);
                        acc[o][2] = fmaf(p[ky + 1][kx],     wv, acc[o][2]);
                        acc[o][3] = fmaf(p[ky + 1][kx + 1], wv, acc[o][3]);
                    }
            }
        }
    }
    #pragma unroll
    for (int o = 0; o < 8; ++o) {
        int oc = ocbase + o;
        float inv = g[oc] * rsqrtf(v[oc] + 1e-5f);
        float bs  = (cb[oc] - m[oc]) * inv + beta[oc];
        float r = fmaxf(fmaxf(fmaxf(acc[o][0] * inv + bs, 0.f), fmaxf(acc[o][1] * inv + bs, 0.f)),
                        fmaxf(fmaxf(acc[o][2] * inv + bs, 0.f), fmaxf(acc[o][3] * inv + bs, 0.f)));
        out[(((size_t)b * 64 + oc) << 6) + (ph << 3) + pw] = r;
    }
}

// ---------------- Head: projection + tanh + analytic quantum map + classifier
// single[i] = prod_{q<=i} cos(theta_q); pair(i,j) = prod_{q=i+1..j} cos(theta_q)
__global__ __launch_bounds__(256) void k_head(const float* __restrict__ h3,
    const float* __restrict__ pjw, const float* __restrict__ pjb,
    const float* __restrict__ cw, const float* __restrict__ cbias,
    float* __restrict__ out)
{
    int wid = (blockIdx.x << 2) + (threadIdx.x >> 6);  // 8192 waves
    int lane = threadIdx.x & 63;
    int b = wid >> 4, k = wid & 15;
    const float* f = h3 + (size_t)b * 4096 + k * 256;
    float fv[4];
    #pragma unroll
    for (int j = 0; j < 4; ++j) fv[j] = f[lane + 64 * j];
    const float* wp = pjw + k * 2048;     // [256][8]
    float wv[4][8];
    #pragma unroll
    for (int j = 0; j < 4; ++j) {
        const float4* q4 = (const float4*)(wp + (lane + 64 * j) * 8);
        float4 lo = q4[0], hi = q4[1];
        wv[j][0] = lo.x; wv[j][1] = lo.y; wv[j][2] = lo.z; wv[j][3] = lo.w;
        wv[j][4] = hi.x; wv[j][5] = hi.y; wv[j][6] = hi.z; wv[j][7] = hi.w;
    }
    float cz[8];
    #pragma unroll
    for (int d = 0; d < 8; ++d) {
        float s = fv[0] * wv[0][d] + fv[1] * wv[1][d] + fv[2] * wv[2][d] + fv[3] * wv[3][d];
        #pragma unroll
        for (int off = 32; off; off >>= 1) s += __shfl_xor(s, off, 64);
        float z = s + pjb[k * 8 + d];
        cz[d] = cosf(0.5f * tanhf(z));
    }
    float qf[36];
    float pp = 1.f;
    #pragma unroll
    for (int i = 0; i < 8; ++i) { pp *= cz[i]; qf[i] = pp; }
    int cnt = 8;
    #pragma unroll
    for (int i = 0; i < 8; ++i) {
        float p2 = 1.f;
        #pragma unroll
        for (int j = i + 1; j < 8; ++j) { p2 *= cz[j]; qf[cnt++] = p2; }
    }
    if (lane < 10) {
        const float* cwp = cw + lane * 576 + k * 36;
        float s = 0.f;
        #pragma unroll
        for (int f2 = 0; f2 < 36; ++f2) s = fmaf(qf[f2], cwp[f2], s);
        if (k == 0) s += cbias[lane];
        atomicAdd(out + b * 10 + lane, s);
    }
}

extern "C" void kernel_launch(void* const* d_in, const int* in_sizes, int n_in,
                              void* d_out, int out_size, void* d_ws, size_t ws_size,
                              hipStream_t stream) {
    const float* x       = (const float*)d_in[0];
    const float* c1w     = (const float*)d_in[1];
    const float* c1b     = (const float*)d_in[2];
    const float* b1g     = (const float*)d_in[3];
    const float* b1b     = (const float*)d_in[4];
    const float* b1m     = (const float*)d_in[5];
    const float* b1v     = (const float*)d_in[6];
    const float* c2w     = (const float*)d_in[7];
    const float* c2b     = (const float*)d_in[8];
    const float* b2g     = (const float*)d_in[9];
    const float* b2b     = (const float*)d_in[10];
    const float* b2m     = (const float*)d_in[11];
    const float* b2v     = (const float*)d_in[12];
    const float* c3w     = (const float*)d_in[13];
    const float* c3b     = (const float*)d_in[14];
    const float* b3g     = (const float*)d_in[15];
    const float* b3b     = (const float*)d_in[16];
    const float* b3m     = (const float*)d_in[17];
    const float* b3v     = (const float*)d_in[18];
    const float* pjw     = (const float*)d_in[19];
    const float* pjb     = (const float*)d_in[20];
    const float* cw      = (const float*)d_in[21];
    const float* cbias   = (const float*)d_in[22];
    float* outp = (float*)d_out;

    float* A  = (float*)d_ws;          // h1: 512x16x32x32 then h3: 512x64x8x8
    float* Bp = A + 8388608;           // h2: 512x32x16x16

    k_conv1<<<1024, 256, 0, stream>>>(x, c1w, c1b, b1g, b1b, b1m, b1v, A);
    k_conv2<<<2048, 256, 0, stream>>>(A, c2w, c2b, b2g, b2b, b2m, b2v, Bp);
    k_conv3<<<1024, 256, 0, stream>>>(Bp, c3w, c3b, b3g, b3b, b3m, b3v, A);
    hipMemsetAsync(d_out, 0, (size_t)out_size * sizeof(float), stream);
    k_head<<<2048, 256, 0, stream>>>(A, pjw, pjb, cw, cbias, outp);
}

// Round 4
// 215.163 us; speedup vs baseline: 1.4467x; 1.4467x over previous
//
#include <hip/hip_runtime.h>
#include <hip/hip_bf16.h>
#include <math.h>

typedef __attribute__((ext_vector_type(8))) short short8;
typedef __attribute__((ext_vector_type(4))) float f32x4;

__device__ __forceinline__ unsigned short f2bf(float f) {
    union { float f; unsigned u; } x; x.f = f;
    unsigned r = x.u + 0x7FFF + ((x.u >> 16) & 1);
    return (unsigned short)(r >> 16);
}

// ---------------- prep: rearrange conv2/conv3 weights into MFMA A-fragment order (bf16)
// wp2[s<5][ocT<2][lane<64][j<8]: A[m=oc=ocT*16+(lane&15)][k=(lane>>4)*8+j], k->(tap=s*2+(k>>4), ic=k&15)
// wp3[tap<9][ocT<4][lane<64][j<8]: ic=(lane>>4)*8+j (32 ic)
// cst2: inv2[32], bs2[32]; cst3: inv3[64], bs3[64]
__global__ void k_prep(const float* __restrict__ w2, const float* __restrict__ w3,
    const float* g2, const float* be2, const float* m2, const float* v2, const float* cb2,
    const float* g3, const float* be3, const float* m3, const float* v3, const float* cb3,
    unsigned short* __restrict__ wp2, unsigned short* __restrict__ wp3,
    float* __restrict__ cst2, float* __restrict__ cst3)
{
    int tid = blockIdx.x * 256 + threadIdx.x;
    if (tid < 5120) {
        int j = tid & 7, lane = (tid >> 3) & 63, o = (tid >> 9) & 1, s = tid >> 10;
        int kl = ((lane >> 4) << 3) + j;
        int tp = s * 2 + (kl >> 4);
        int ic = kl & 15;
        int oc = o * 16 + (lane & 15);
        float val = (tp < 9) ? w2[(oc * 16 + ic) * 9 + tp] : 0.f;
        wp2[tid] = f2bf(val);
    } else if (tid < 5120 + 18432) {
        int idx = tid - 5120;
        int j = idx & 7, lane = (idx >> 3) & 63, o = (idx >> 9) & 3, tap = idx >> 11;
        int ic = ((lane >> 4) << 3) + j;
        int oc = o * 16 + (lane & 15);
        wp3[idx] = f2bf(w3[(oc * 32 + ic) * 9 + tap]);
    } else if (tid < 5120 + 18432 + 96) {
        int c = tid - 23552;
        if (c < 32) {
            float inv = g2[c] * rsqrtf(v2[c] + 1e-5f);
            cst2[c] = inv;
            cst2[32 + c] = (cb2[c] - m2[c]) * inv + be2[c];
        } else {
            int c3 = c - 32;
            float inv = g3[c3] * rsqrtf(v3[c3] + 1e-5f);
            cst3[c3] = inv;
            cst3[64 + c3] = (cb3[c3] - m3[c3]) * inv + be3[c3];
        }
    }
}

// ---------------- Layer 1 (fp32 VALU): conv 3->16 + bn + relu + pool -> 16x32x32
__global__ __launch_bounds__(256) void k_conv1(const float* __restrict__ x,
    const float* __restrict__ w, const float* __restrict__ cb,
    const float* __restrict__ g, const float* __restrict__ beta,
    const float* __restrict__ m, const float* __restrict__ v,
    float* __restrict__ out)
{
    __shared__ float tile[3 * 34 * 66];
    int bid = blockIdx.x;
    int b = bid >> 1, half = bid & 1;
    const float* img = x + (size_t)b * 3 * 4096;
    int y0 = 32 * half - 1;
    for (int idx = threadIdx.x; idx < 6732; idx += 256) {
        int ic = idx / 2244, rem = idx % 2244;
        int yy = rem / 66, xxp = rem % 66;
        int y = y0 + yy, xx = xxp - 1;
        float val = 0.f;
        if ((unsigned)y < 64u && (unsigned)xx < 64u) val = img[ic * 4096 + y * 64 + xx];
        tile[idx] = val;
    }
    __syncthreads();
    #pragma unroll 1
    for (int it = 0; it < 2; ++it) {
        int pos = threadIdx.x + it * 256;
        int pw = pos & 31, phl = pos >> 5;
        float p[3][4][4];
        #pragma unroll
        for (int ic = 0; ic < 3; ++ic)
            #pragma unroll
            for (int dy = 0; dy < 4; ++dy)
                #pragma unroll
                for (int dx = 0; dx < 4; ++dx)
                    p[ic][dy][dx] = tile[ic * 2244 + (2 * phl + dy) * 66 + 2 * pw + dx];
        float* op = out + (size_t)b * 16384 + (half * 16 + phl) * 32 + pw;
        #pragma unroll
        for (int oc = 0; oc < 16; ++oc) {
            float inv = g[oc] * rsqrtf(v[oc] + 1e-5f);
            float bs  = (cb[oc] - m[oc]) * inv + beta[oc];
            float a0 = 0.f, a1 = 0.f, a2 = 0.f, a3 = 0.f;
            #pragma unroll
            for (int ic = 0; ic < 3; ++ic)
                #pragma unroll
                for (int ky = 0; ky < 3; ++ky)
                    #pragma unroll
                    for (int kx = 0; kx < 3; ++kx) {
                        float wv = w[((oc * 3 + ic) * 3 + ky) * 3 + kx];
                        a0 = fmaf(p[ic][ky][kx],         wv, a0);
                        a1 = fmaf(p[ic][ky][kx + 1],     wv, a1);
                        a2 = fmaf(p[ic][ky + 1][kx],     wv, a2);
                        a3 = fmaf(p[ic][ky + 1][kx + 1], wv, a3);
                    }
            float r = fmaxf(fmaxf(fmaxf(a0 * inv + bs, 0.f), fmaxf(a1 * inv + bs, 0.f)),
                            fmaxf(fmaxf(a2 * inv + bs, 0.f), fmaxf(a3 * inv + bs, 0.f)));
            op[oc * 1024] = r;
        }
    }
}

// ---------------- Layer 2 (MFMA): conv 16->32 + bn + relu + pool -> 32x16x16
// grid 1024 = (b, half). LDS x2[18 rows][34 x][16 ic] bf16. 4 waves x 4 conv-rows.
// A=weights (m=oc), B=input (n=x). K-step = 2 taps x 16 ic, 5 steps (last half zero-padded).
__global__ __launch_bounds__(256) void k_conv2m(const float* __restrict__ in,
    const unsigned short* __restrict__ wp, const float* __restrict__ cst,
    float* __restrict__ out)
{
    __shared__ __align__(16) unsigned short x2[612 * 16];   // 19584 B
    int bid = blockIdx.x;
    int b = bid >> 1, h = bid & 1;
    int t = threadIdx.x;
    const float* src = in + (size_t)b * 16384;
    #pragma unroll 1
    for (int i = 0; i < 20; ++i) {
        int idx = t + i * 256;
        if (idx < 4896) {
            int icp = idx / 612;
            int pos = idx - icp * 612;
            int y = pos / 34, xx = pos - y * 34;
            int gy = h * 16 + y - 1, gx = xx - 1;
            float v0 = 0.f, v1 = 0.f;
            if ((unsigned)gy < 32u && (unsigned)gx < 32u) {
                const float* pb = src + (icp * 2) * 1024 + gy * 32 + gx;
                v0 = pb[0]; v1 = pb[1024];
            }
            unsigned pk = (unsigned)f2bf(v0) | ((unsigned)f2bf(v1) << 16);
            ((unsigned*)x2)[pos * 8 + icp] = pk;
        }
    }
    int lane = t & 63, w = t >> 6;
    int q = lane >> 4, xl = lane & 15;
    short8 A[5][2];
    #pragma unroll
    for (int s = 0; s < 5; ++s)
        #pragma unroll
        for (int o = 0; o < 2; ++o)
            A[s][o] = *(const short8*)(wp + (((s * 2 + o) * 64 + lane) << 3));
    int dyA[5], dxA[5];
    #pragma unroll
    for (int s = 0; s < 5; ++s) {
        int tp = s * 2 + (q >> 1); if (tp > 8) tp = 8;
        int d3 = tp / 3;
        dyA[s] = d3 - 1; dxA[s] = tp - d3 * 3 - 1;
    }
    __syncthreads();
    f32x4 acc[4][2][2];
    #pragma unroll
    for (int r = 0; r < 4; ++r)
        #pragma unroll
        for (int xT = 0; xT < 2; ++xT)
            #pragma unroll
            for (int o = 0; o < 2; ++o)
                acc[r][xT][o] = (f32x4){0.f, 0.f, 0.f, 0.f};
    #pragma unroll
    for (int r = 0; r < 4; ++r) {
        int ry = w * 4 + r + 1;
        #pragma unroll
        for (int xT = 0; xT < 2; ++xT) {
            int xb = xT * 16 + xl + 1;
            #pragma unroll
            for (int s = 0; s < 5; ++s) {
                int pos = (ry + dyA[s]) * 34 + xb + dxA[s];
                short8 B = *(const short8*)(x2 + pos * 16 + (q & 1) * 8);
                acc[r][xT][0] = __builtin_amdgcn_mfma_f32_16x16x32_bf16(A[s][0], B, acc[r][xT][0], 0, 0, 0);
                acc[r][xT][1] = __builtin_amdgcn_mfma_f32_16x16x32_bf16(A[s][1], B, acc[r][xT][1], 0, 0, 0);
            }
        }
    }
    // epilogue: bn+relu+pool; D: col(x)=lane&15, row(oc-part)=q*4+reg
    #pragma unroll
    for (int oT = 0; oT < 2; ++oT) {
        #pragma unroll
        for (int reg = 0; reg < 4; ++reg) {
            int oc = oT * 16 + q * 4 + reg;
            float inv = cst[oc], bs = cst[32 + oc];
            #pragma unroll
            for (int rp = 0; rp < 2; ++rp) {
                #pragma unroll
                for (int xT = 0; xT < 2; ++xT) {
                    float v0 = fmaxf(acc[rp * 2][xT][oT][reg] * inv + bs, 0.f);
                    float v1 = fmaxf(acc[rp * 2 + 1][xT][oT][reg] * inv + bs, 0.f);
                    float vm = fmaxf(v0, v1);
                    float vo = fmaxf(vm, __shfl_xor(vm, 1, 64));
                    if (!(lane & 1)) {
                        int py = h * 8 + w * 2 + rp;
                        int px = xT * 8 + (xl >> 1);
                        out[(((size_t)b * 32 + oc) << 8) + py * 16 + px] = vo;
                    }
                }
            }
        }
    }
}

// ---------------- Layer 3 (MFMA): conv 32->64 + bn + relu + pool -> 64x8x8
// grid 512 = b. LDS x3[324 pos][40 ic-padded] bf16 (stride 80B, 16B-aligned frags).
// K-step = 1 tap x 32 ic, 9 steps. oc processed as 2 pairs of 16x16 tiles.
__global__ __launch_bounds__(256) void k_conv3m(const float* __restrict__ in,
    const unsigned short* __restrict__ wp, const float* __restrict__ cst,
    float* __restrict__ out)
{
    __shared__ __align__(16) unsigned short x3[324 * 40];   // 25920 B
    int b = blockIdx.x;
    int t = threadIdx.x;
    const float* src = in + (size_t)b * 8192;
    #pragma unroll 1
    for (int i = 0; i < 11; ++i) {
        int idx = t + i * 256;
        if (idx < 2592) {
            int icq = idx / 324;
            int pos = idx - icq * 324;
            int y = pos / 18, xx = pos - y * 18;
            int gy = y - 1, gx = xx - 1;
            float v0 = 0.f, v1 = 0.f, v2 = 0.f, v3 = 0.f;
            if ((unsigned)gy < 16u && (unsigned)gx < 16u) {
                const float* pb = src + icq * 1024 + gy * 16 + gx;
                v0 = pb[0]; v1 = pb[256]; v2 = pb[512]; v3 = pb[768];
            }
            uint2 pk;
            pk.x = (unsigned)f2bf(v0) | ((unsigned)f2bf(v1) << 16);
            pk.y = (unsigned)f2bf(v2) | ((unsigned)f2bf(v3) << 16);
            ((uint2*)x3)[pos * 10 + icq] = pk;
        }
    }
    __syncthreads();
    int lane = t & 63, w = t >> 6;
    int q = lane >> 4, xl = lane & 15;
    #pragma unroll 1
    for (int op = 0; op < 2; ++op) {
        short8 A[9][2];
        #pragma unroll
        for (int tap = 0; tap < 9; ++tap)
            #pragma unroll
            for (int tt = 0; tt < 2; ++tt)
                A[tap][tt] = *(const short8*)(wp + (((tap * 4 + op * 2 + tt) * 64 + lane) << 3));
        f32x4 acc[4][2];
        #pragma unroll
        for (int r = 0; r < 4; ++r) {
            acc[r][0] = (f32x4){0.f, 0.f, 0.f, 0.f};
            acc[r][1] = (f32x4){0.f, 0.f, 0.f, 0.f};
        }
        #pragma unroll
        for (int r = 0; r < 4; ++r) {
            int ry = w * 4 + r + 1;
            #pragma unroll
            for (int tap = 0; tap < 9; ++tap) {
                int pos = (ry + tap / 3 - 1) * 18 + xl + (tap % 3);
                short8 B = *(const short8*)(x3 + pos * 40 + q * 8);
                acc[r][0] = __builtin_amdgcn_mfma_f32_16x16x32_bf16(A[tap][0], B, acc[r][0], 0, 0, 0);
                acc[r][1] = __builtin_amdgcn_mfma_f32_16x16x32_bf16(A[tap][1], B, acc[r][1], 0, 0, 0);
            }
        }
        #pragma unroll
        for (int tt = 0; tt < 2; ++tt) {
            #pragma unroll
            for (int reg = 0; reg < 4; ++reg) {
                int oc = (op * 2 + tt) * 16 + q * 4 + reg;
                float inv = cst[oc], bs = cst[64 + oc];
                #pragma unroll
                for (int rp = 0; rp < 2; ++rp) {
                    float v0 = fmaxf(acc[rp * 2][tt][reg] * inv + bs, 0.f);
                    float v1 = fmaxf(acc[rp * 2 + 1][tt][reg] * inv + bs, 0.f);
                    float vm = fmaxf(v0, v1);
                    float vo = fmaxf(vm, __shfl_xor(vm, 1, 64));
                    if (!(lane & 1))
                        out[(((size_t)b * 64 + oc) << 6) + (w * 2 + rp) * 8 + (xl >> 1)] = vo;
                }
            }
        }
    }
}

// ---------------- Head: block per b, no atomics.
// single[i]=prod_{q<=i}cos(theta_q); pair(i,j)=prod_{i<q<=j}cos(theta_q)
__global__ __launch_bounds__(256) void k_head(const float* __restrict__ h3,
    const float* __restrict__ pjw, const float* __restrict__ pjb,
    const float* __restrict__ cw, const float* __restrict__ cbias,
    float* __restrict__ out)
{
    __shared__ float czs[16][8];
    __shared__ float part[16][10];
    int b = blockIdx.x;
    int t = threadIdx.x;
    int w = t >> 6, lane = t & 63;
    #pragma unroll 1
    for (int kk = 0; kk < 4; ++kk) {
        int k = w * 4 + kk;
        const float* f = h3 + (size_t)b * 4096 + k * 256;
        float fv[4];
        #pragma unroll
        for (int j = 0; j < 4; ++j) fv[j] = f[lane + 64 * j];
        const float* wpk = pjw + k * 2048;
        float wv[4][8];
        #pragma unroll
        for (int j = 0; j < 4; ++j) {
            const float4* q4 = (const float4*)(wpk + (lane + 64 * j) * 8);
            float4 lo = q4[0], hi = q4[1];
            wv[j][0] = lo.x; wv[j][1] = lo.y; wv[j][2] = lo.z; wv[j][3] = lo.w;
            wv[j][4] = hi.x; wv[j][5] = hi.y; wv[j][6] = hi.z; wv[j][7] = hi.w;
        }
        float cz[8];
        #pragma unroll
        for (int d = 0; d < 8; ++d) {
            float s = fv[0] * wv[0][d] + fv[1] * wv[1][d] + fv[2] * wv[2][d] + fv[3] * wv[3][d];
            #pragma unroll
            for (int off = 32; off; off >>= 1) s += __shfl_xor(s, off, 64);
            float z = s + pjb[k * 8 + d];
            cz[d] = cosf(0.5f * tanhf(z));
        }
        if (lane < 8) {
            float a0 = (lane & 1) ? cz[1] : cz[0];
            float a1 = (lane & 1) ? cz[3] : cz[2];
            float a2 = (lane & 1) ? cz[5] : cz[4];
            float a3 = (lane & 1) ? cz[7] : cz[6];
            float b0 = (lane & 2) ? a1 : a0;
            float b1 = (lane & 2) ? a3 : a2;
            czs[k][lane] = (lane & 4) ? b1 : b0;
        }
    }
    __syncthreads();
    if (t < 160) {
        int k = t / 10, c = t - (t / 10) * 10;
        float cz[8];
        #pragma unroll
        for (int i = 0; i < 8; ++i) cz[i] = czs[k][i];
        const float* cwp = cw + c * 576 + k * 36;
        float s = 0.f;
        float pp = 1.f;
        #pragma unroll
        for (int i = 0; i < 8; ++i) { pp *= cz[i]; s = fmaf(pp, cwp[i], s); }
        int cnt = 8;
        #pragma unroll
        for (int i = 0; i < 8; ++i) {
            float p2 = 1.f;
            #pragma unroll
            for (int j = i + 1; j < 8; ++j) { p2 *= cz[j]; s = fmaf(p2, cwp[cnt++], s); }
        }
        part[k][c] = s;
    }
    __syncthreads();
    if (t < 10) {
        float s = cbias[t];
        #pragma unroll
        for (int k = 0; k < 16; ++k) s += part[k][t];
        out[b * 10 + t] = s;
    }
}

extern "C" void kernel_launch(void* const* d_in, const int* in_sizes, int n_in,
                              void* d_out, int out_size, void* d_ws, size_t ws_size,
                              hipStream_t stream) {
    const float* x     = (const float*)d_in[0];
    const float* c1w   = (const float*)d_in[1];
    const float* c1b   = (const float*)d_in[2];
    const float* b1g   = (const float*)d_in[3];
    const float* b1b   = (const float*)d_in[4];
    const float* b1m   = (const float*)d_in[5];
    const float* b1v   = (const float*)d_in[6];
    const float* c2w   = (const float*)d_in[7];
    const float* c2b   = (const float*)d_in[8];
    const float* b2g   = (const float*)d_in[9];
    const float* b2b   = (const float*)d_in[10];
    const float* b2m   = (const float*)d_in[11];
    const float* b2v   = (const float*)d_in[12];
    const float* c3w   = (const float*)d_in[13];
    const float* c3b   = (const float*)d_in[14];
    const float* b3g   = (const float*)d_in[15];
    const float* b3b   = (const float*)d_in[16];
    const float* b3m   = (const float*)d_in[17];
    const float* b3v   = (const float*)d_in[18];
    const float* pjw   = (const float*)d_in[19];
    const float* pjb   = (const float*)d_in[20];
    const float* cw    = (const float*)d_in[21];
    const float* cbias = (const float*)d_in[22];
    float* outp = (float*)d_out;

    float* A  = (float*)d_ws;              // h1 [512][16][32][32] then h3 [512][64][8][8]
    float* Bp = A + 8388608;               // h2 [512][32][16][16]
    unsigned char* prep = (unsigned char*)(Bp + 4194304);
    unsigned short* wp2 = (unsigned short*)prep;             // 5120 bf16
    unsigned short* wp3 = (unsigned short*)(prep + 16384);   // 18432 bf16
    float* cst2 = (float*)(prep + 16384 + 36864);            // inv2[32], bs2[32]
    float* cst3 = cst2 + 64;                                 // inv3[64], bs3[64]

    k_prep<<<93, 256, 0, stream>>>(c2w, c3w, b2g, b2b, b2m, b2v, c2b,
                                   b3g, b3b, b3m, b3v, c3b, wp2, wp3, cst2, cst3);
    k_conv1<<<1024, 256, 0, stream>>>(x, c1w, c1b, b1g, b1b, b1m, b1v, A);
    k_conv2m<<<1024, 256, 0, stream>>>(A, wp2, cst2, Bp);
    k_conv3m<<<512, 256, 0, stream>>>(Bp, wp3, cst3, A);
    k_head<<<512, 256, 0, stream>>>(A, pjw, pjb, cw, cbias, outp);
}

// Round 5
// 187.286 us; speedup vs baseline: 1.6620x; 1.1488x over previous
//
#include <hip/hip_runtime.h>
#include <hip/hip_bf16.h>
#include <math.h>

typedef __attribute__((ext_vector_type(8))) short short8;
typedef __attribute__((ext_vector_type(4))) float f32x4;

__device__ __forceinline__ unsigned short f2bf(float f) {
    union { float f; unsigned u; } x; x.f = f;
    unsigned r = x.u + 0x7FFF + ((x.u >> 16) & 1);
    return (unsigned short)(r >> 16);
}

__device__ __forceinline__ short8 mk8(uint2 a, uint2 b) {
    union { uint2 u[2]; short8 s; } x;
    x.u[0] = a; x.u[1] = b;
    return x.s;
}

// ---------------- prep: rearrange weights into MFMA A-fragment order (bf16)
// wp2[s<5][ocT<2][lane<64][j<8]: k=(lane>>4)*8+j -> (tap=s*2+(k>>4), ic=k&15)
// wp3[tap<9][ocT<4][lane<64][j<8]: ic=(lane>>4)*8+j
// wp1[s<2][lane<64][j<8]: s0: k=tap*4+ic (taps 0..7, ic<3 real); s1: k<3 -> ic of tap8
// cst2: inv2[32], bs2[32]; cst3: inv3[64], bs3[64]; cst1: inv1[16], bs1[16]
__global__ void k_prep(const float* __restrict__ w2, const float* __restrict__ w3,
    const float* g2, const float* be2, const float* m2, const float* v2, const float* cb2,
    const float* g3, const float* be3, const float* m3, const float* v3, const float* cb3,
    const float* __restrict__ w1,
    const float* g1, const float* be1, const float* m1, const float* v1, const float* cb1,
    unsigned short* __restrict__ wp2, unsigned short* __restrict__ wp3,
    unsigned short* __restrict__ wp1,
    float* __restrict__ cst2, float* __restrict__ cst3, float* __restrict__ cst1)
{
    int tid = blockIdx.x * 256 + threadIdx.x;
    if (tid < 5120) {
        int j = tid & 7, lane = (tid >> 3) & 63, o = (tid >> 9) & 1, s = tid >> 10;
        int kl = ((lane >> 4) << 3) + j;
        int tp = s * 2 + (kl >> 4);
        int ic = kl & 15;
        int oc = o * 16 + (lane & 15);
        float val = (tp < 9) ? w2[(oc * 16 + ic) * 9 + tp] : 0.f;
        wp2[tid] = f2bf(val);
    } else if (tid < 23552) {
        int idx = tid - 5120;
        int j = idx & 7, lane = (idx >> 3) & 63, o = (idx >> 9) & 3, tap = idx >> 11;
        int ic = ((lane >> 4) << 3) + j;
        int oc = o * 16 + (lane & 15);
        wp3[idx] = f2bf(w3[(oc * 32 + ic) * 9 + tap]);
    } else if (tid < 23648) {
        int c = tid - 23552;
        if (c < 32) {
            float inv = g2[c] * rsqrtf(v2[c] + 1e-5f);
            cst2[c] = inv;
            cst2[32 + c] = (cb2[c] - m2[c]) * inv + be2[c];
        } else {
            int c3 = c - 32;
            float inv = g3[c3] * rsqrtf(v3[c3] + 1e-5f);
            cst3[c3] = inv;
            cst3[64 + c3] = (cb3[c3] - m3[c3]) * inv + be3[c3];
        }
    } else if (tid < 24672) {
        int idx = tid - 23648;
        int j = idx & 7, lane = (idx >> 3) & 63, s = (idx >> 9) & 1;
        int k = ((lane >> 4) << 3) + j;
        int oc = lane & 15;
        float val = 0.f;
        if (s == 0) {
            int tap = k >> 2, ic = k & 3;
            if (ic < 3) val = w1[(oc * 3 + ic) * 9 + tap];
        } else {
            if (k < 3) val = w1[(oc * 3 + k) * 9 + 8];
        }
        wp1[idx] = f2bf(val);
    } else if (tid < 24688) {
        int c = tid - 24672;
        float inv = g1[c] * rsqrtf(v1[c] + 1e-5f);
        cst1[c] = inv;
        cst1[16 + c] = (cb1[c] - m1[c]) * inv + be1[c];
    }
}

// ---------------- Layer 1 (MFMA): conv 3->16 + bn + relu + pool -> 16x32x32
// grid 1024 = (b, half). LDS xs[34 rows][66 x][4 ic] bf16 (8B per pos).
// K-pack: k = tap*4+ic; step0 = taps 0..7 (one K=32 MFMA), step1 = tap 8 (A zero-padded).
__global__ __launch_bounds__(256) void k_conv1m(const float* __restrict__ x,
    const unsigned short* __restrict__ wp, const float* __restrict__ cst,
    float* __restrict__ out)
{
    __shared__ __align__(16) unsigned short xs[2244 * 4];   // 17952 B
    int bid = blockIdx.x;
    int b = bid >> 1, h = bid & 1;
    int t = threadIdx.x;
    const float* img = x + (size_t)b * 3 * 4096;
    int y0 = h * 32 - 1;
    #pragma unroll 1
    for (int i = 0; i < 9; ++i) {
        int idx = t + i * 256;
        if (idx < 2244) {
            int y = idx / 66, xx = idx - y * 66;
            int gy = y0 + y, gx = xx - 1;
            float v0 = 0.f, v1 = 0.f, v2 = 0.f;
            if ((unsigned)gy < 64u && (unsigned)gx < 64u) {
                const float* pb = img + gy * 64 + gx;
                v0 = pb[0]; v1 = pb[4096]; v2 = pb[8192];
            }
            uint2 pk;
            pk.x = (unsigned)f2bf(v0) | ((unsigned)f2bf(v1) << 16);
            pk.y = (unsigned)f2bf(v2);
            ((uint2*)xs)[idx] = pk;
        }
    }
    int lane = t & 63, w = t >> 6;
    int q = lane >> 4, xl = lane & 15;
    short8 A0 = *(const short8*)(wp + (lane << 3));
    short8 A1 = *(const short8*)(wp + ((64 + lane) << 3));
    int t0 = 2 * q, t1 = 2 * q + 1;
    int dy0 = t0 / 3 - 1, dx0 = t0 % 3 - 1;
    int dy1 = t1 / 3 - 1, dx1 = t1 % 3 - 1;
    float invr[4], bsr[4];
    #pragma unroll
    for (int reg = 0; reg < 4; ++reg) {
        int oc = q * 4 + reg;
        invr[reg] = cst[oc]; bsr[reg] = cst[16 + oc];
    }
    __syncthreads();
    #pragma unroll 1
    for (int xT = 0; xT < 4; ++xT) {
        int xb = xT * 16 + xl + 1;
        float pv[4];
        #pragma unroll
        for (int r = 0; r < 8; ++r) {
            int ly = w * 8 + r + 1;
            const uint2* base = (const uint2*)xs;
            uint2 ua = base[(ly + dy0) * 66 + xb + dx0];
            uint2 ub = base[(ly + dy1) * 66 + xb + dx1];
            uint2 uc = base[(ly + 1) * 66 + xb + 1];
            f32x4 acc = (f32x4){0.f, 0.f, 0.f, 0.f};
            acc = __builtin_amdgcn_mfma_f32_16x16x32_bf16(A0, mk8(ua, ub), acc, 0, 0, 0);
            acc = __builtin_amdgcn_mfma_f32_16x16x32_bf16(A1, mk8(uc, uc), acc, 0, 0, 0);
            #pragma unroll
            for (int reg = 0; reg < 4; ++reg) {
                float val = fmaxf(acc[reg] * invr[reg] + bsr[reg], 0.f);
                if (r & 1) {
                    float vm = fmaxf(val, pv[reg]);
                    float vo = fmaxf(vm, __shfl_xor(vm, 1, 64));
                    if (!(lane & 1)) {
                        int oc = q * 4 + reg;
                        int py = h * 16 + w * 4 + (r >> 1);
                        int px = xT * 8 + (xl >> 1);
                        out[(((size_t)b * 16 + oc) << 10) + py * 32 + px] = vo;
                    }
                } else {
                    pv[reg] = val;
                }
            }
        }
    }
}

// ---------------- Layer 2 (MFMA): conv 16->32 + bn + relu + pool -> 32x16x16
// grid 1024 = (b, half). LDS x2[612 pos][20 shorts] (16 ic + 4 pad -> conflict-free).
__global__ __launch_bounds__(256) void k_conv2m(const float* __restrict__ in,
    const unsigned short* __restrict__ wp, const float* __restrict__ cst,
    float* __restrict__ out)
{
    __shared__ __align__(16) unsigned short x2[612 * 20];   // 24480 B
    int bid = blockIdx.x;
    int b = bid >> 1, h = bid & 1;
    int t = threadIdx.x;
    const float* src = in + (size_t)b * 16384;
    #pragma unroll 1
    for (int i = 0; i < 20; ++i) {
        int idx = t + i * 256;
        if (idx < 4896) {
            int icp = idx / 612;
            int pos = idx - icp * 612;
            int y = pos / 34, xx = pos - y * 34;
            int gy = h * 16 + y - 1, gx = xx - 1;
            float v0 = 0.f, v1 = 0.f;
            if ((unsigned)gy < 32u && (unsigned)gx < 32u) {
                const float* pb = src + (icp * 2) * 1024 + gy * 32 + gx;
                v0 = pb[0]; v1 = pb[1024];
            }
            unsigned pk = (unsigned)f2bf(v0) | ((unsigned)f2bf(v1) << 16);
            ((unsigned*)x2)[pos * 10 + icp] = pk;
        }
    }
    int lane = t & 63, w = t >> 6;
    int q = lane >> 4, xl = lane & 15;
    short8 A[5][2];
    #pragma unroll
    for (int s = 0; s < 5; ++s)
        #pragma unroll
        for (int o = 0; o < 2; ++o)
            A[s][o] = *(const short8*)(wp + (((s * 2 + o) * 64 + lane) << 3));
    int dyA[5], dxA[5];
    #pragma unroll
    for (int s = 0; s < 5; ++s) {
        int tp = s * 2 + (q >> 1); if (tp > 8) tp = 8;
        int d3 = tp / 3;
        dyA[s] = d3 - 1; dxA[s] = tp - d3 * 3 - 1;
    }
    __syncthreads();
    f32x4 acc[4][2][2];
    #pragma unroll
    for (int r = 0; r < 4; ++r)
        #pragma unroll
        for (int xT = 0; xT < 2; ++xT)
            #pragma unroll
            for (int o = 0; o < 2; ++o)
                acc[r][xT][o] = (f32x4){0.f, 0.f, 0.f, 0.f};
    #pragma unroll
    for (int r = 0; r < 4; ++r) {
        int ry = w * 4 + r + 1;
        #pragma unroll
        for (int xT = 0; xT < 2; ++xT) {
            int xb = xT * 16 + xl + 1;
            #pragma unroll
            for (int s = 0; s < 5; ++s) {
                int pos = (ry + dyA[s]) * 34 + xb + dxA[s];
                const uint2* bp = (const uint2*)x2 + pos * 5 + (q & 1) * 2;
                short8 B = mk8(bp[0], bp[1]);
                acc[r][xT][0] = __builtin_amdgcn_mfma_f32_16x16x32_bf16(A[s][0], B, acc[r][xT][0], 0, 0, 0);
                acc[r][xT][1] = __builtin_amdgcn_mfma_f32_16x16x32_bf16(A[s][1], B, acc[r][xT][1], 0, 0, 0);
            }
        }
    }
    #pragma unroll
    for (int oT = 0; oT < 2; ++oT) {
        #pragma unroll
        for (int reg = 0; reg < 4; ++reg) {
            int oc = oT * 16 + q * 4 + reg;
            float inv = cst[oc], bs = cst[32 + oc];
            #pragma unroll
            for (int rp = 0; rp < 2; ++rp) {
                #pragma unroll
                for (int xT = 0; xT < 2; ++xT) {
                    float v0 = fmaxf(acc[rp * 2][xT][oT][reg] * inv + bs, 0.f);
                    float v1 = fmaxf(acc[rp * 2 + 1][xT][oT][reg] * inv + bs, 0.f);
                    float vm = fmaxf(v0, v1);
                    float vo = fmaxf(vm, __shfl_xor(vm, 1, 64));
                    if (!(lane & 1)) {
                        int py = h * 8 + w * 2 + rp;
                        int px = xT * 8 + (xl >> 1);
                        out[(((size_t)b * 32 + oc) << 8) + py * 16 + px] = vo;
                    }
                }
            }
        }
    }
}

// ---------------- Layer 3 (MFMA): conv 32->64 + bn + relu + pool -> 64x8x8
__global__ __launch_bounds__(256) void k_conv3m(const float* __restrict__ in,
    const unsigned short* __restrict__ wp, const float* __restrict__ cst,
    float* __restrict__ out)
{
    __shared__ __align__(16) unsigned short x3[324 * 40];   // 25920 B
    int b = blockIdx.x;
    int t = threadIdx.x;
    const float* src = in + (size_t)b * 8192;
    #pragma unroll 1
    for (int i = 0; i < 11; ++i) {
        int idx = t + i * 256;
        if (idx < 2592) {
            int icq = idx / 324;
            int pos = idx - icq * 324;
            int y = pos / 18, xx = pos - y * 18;
            int gy = y - 1, gx = xx - 1;
            float v0 = 0.f, v1 = 0.f, v2 = 0.f, v3 = 0.f;
            if ((unsigned)gy < 16u && (unsigned)gx < 16u) {
                const float* pb = src + icq * 1024 + gy * 16 + gx;
                v0 = pb[0]; v1 = pb[256]; v2 = pb[512]; v3 = pb[768];
            }
            uint2 pk;
            pk.x = (unsigned)f2bf(v0) | ((unsigned)f2bf(v1) << 16);
            pk.y = (unsigned)f2bf(v2) | ((unsigned)f2bf(v3) << 16);
            ((uint2*)x3)[pos * 10 + icq] = pk;
        }
    }
    __syncthreads();
    int lane = t & 63, w = t >> 6;
    int q = lane >> 4, xl = lane & 15;
    #pragma unroll 1
    for (int op = 0; op < 2; ++op) {
        short8 A[9][2];
        #pragma unroll
        for (int tap = 0; tap < 9; ++tap)
            #pragma unroll
            for (int tt = 0; tt < 2; ++tt)
                A[tap][tt] = *(const short8*)(wp + (((tap * 4 + op * 2 + tt) * 64 + lane) << 3));
        f32x4 acc[4][2];
        #pragma unroll
        for (int r = 0; r < 4; ++r) {
            acc[r][0] = (f32x4){0.f, 0.f, 0.f, 0.f};
            acc[r][1] = (f32x4){0.f, 0.f, 0.f, 0.f};
        }
        #pragma unroll
        for (int r = 0; r < 4; ++r) {
            int ry = w * 4 + r + 1;
            #pragma unroll
            for (int tap = 0; tap < 9; ++tap) {
                int pos = (ry + tap / 3 - 1) * 18 + xl + (tap % 3);
                short8 B = *(const short8*)(x3 + pos * 40 + q * 8);
                acc[r][0] = __builtin_amdgcn_mfma_f32_16x16x32_bf16(A[tap][0], B, acc[r][0], 0, 0, 0);
                acc[r][1] = __builtin_amdgcn_mfma_f32_16x16x32_bf16(A[tap][1], B, acc[r][1], 0, 0, 0);
            }
        }
        #pragma unroll
        for (int tt = 0; tt < 2; ++tt) {
            #pragma unroll
            for (int reg = 0; reg < 4; ++reg) {
                int oc = (op * 2 + tt) * 16 + q * 4 + reg;
                float inv = cst[oc], bs = cst[64 + oc];
                #pragma unroll
                for (int rp = 0; rp < 2; ++rp) {
                    float v0 = fmaxf(acc[rp * 2][tt][reg] * inv + bs, 0.f);
                    float v1 = fmaxf(acc[rp * 2 + 1][tt][reg] * inv + bs, 0.f);
                    float vm = fmaxf(v0, v1);
                    float vo = fmaxf(vm, __shfl_xor(vm, 1, 64));
                    if (!(lane & 1))
                        out[(((size_t)b * 64 + oc) << 6) + (w * 2 + rp) * 8 + (xl >> 1)] = vo;
                }
            }
        }
    }
}

// ---------------- Head: block per b, no atomics.
__global__ __launch_bounds__(256) void k_head(const float* __restrict__ h3,
    const float* __restrict__ pjw, const float* __restrict__ pjb,
    const float* __restrict__ cw, const float* __restrict__ cbias,
    float* __restrict__ out)
{
    __shared__ float czs[16][8];
    __shared__ float part[16][10];
    int b = blockIdx.x;
    int t = threadIdx.x;
    int w = t >> 6, lane = t & 63;
    #pragma unroll 1
    for (int kk = 0; kk < 4; ++kk) {
        int k = w * 4 + kk;
        const float* f = h3 + (size_t)b * 4096 + k * 256;
        float fv[4];
        #pragma unroll
        for (int j = 0; j < 4; ++j) fv[j] = f[lane + 64 * j];
        const float* wpk = pjw + k * 2048;
        float wv[4][8];
        #pragma unroll
        for (int j = 0; j < 4; ++j) {
            const float4* q4 = (const float4*)(wpk + (lane + 64 * j) * 8);
            float4 lo = q4[0], hi = q4[1];
            wv[j][0] = lo.x; wv[j][1] = lo.y; wv[j][2] = lo.z; wv[j][3] = lo.w;
            wv[j][4] = hi.x; wv[j][5] = hi.y; wv[j][6] = hi.z; wv[j][7] = hi.w;
        }
        float cz[8];
        #pragma unroll
        for (int d = 0; d < 8; ++d) {
            float s = fv[0] * wv[0][d] + fv[1] * wv[1][d] + fv[2] * wv[2][d] + fv[3] * wv[3][d];
            #pragma unroll
            for (int off = 32; off; off >>= 1) s += __shfl_xor(s, off, 64);
            float z = s + pjb[k * 8 + d];
            cz[d] = cosf(0.5f * tanhf(z));
        }
        if (lane < 8) {
            float a0 = (lane & 1) ? cz[1] : cz[0];
            float a1 = (lane & 1) ? cz[3] : cz[2];
            float a2 = (lane & 1) ? cz[5] : cz[4];
            float a3 = (lane & 1) ? cz[7] : cz[6];
            float b0 = (lane & 2) ? a1 : a0;
            float b1 = (lane & 2) ? a3 : a2;
            czs[k][lane] = (lane & 4) ? b1 : b0;
        }
    }
    __syncthreads();
    if (t < 160) {
        int k = t / 10, c = t - (t / 10) * 10;
        float cz[8];
        #pragma unroll
        for (int i = 0; i < 8; ++i) cz[i] = czs[k][i];
        const float* cwp = cw + c * 576 + k * 36;
        float s = 0.f;
        float pp = 1.f;
        #pragma unroll
        for (int i = 0; i < 8; ++i) { pp *= cz[i]; s = fmaf(pp, cwp[i], s); }
        int cnt = 8;
        #pragma unroll
        for (int i = 0; i < 8; ++i) {
            float p2 = 1.f;
            #pragma unroll
            for (int j = i + 1; j < 8; ++j) { p2 *= cz[j]; s = fmaf(p2, cwp[cnt++], s); }
        }
        part[k][c] = s;
    }
    __syncthreads();
    if (t < 10) {
        float s = cbias[t];
        #pragma unroll
        for (int k = 0; k < 16; ++k) s += part[k][t];
        out[b * 10 + t] = s;
    }
}

extern "C" void kernel_launch(void* const* d_in, const int* in_sizes, int n_in,
                              void* d_out, int out_size, void* d_ws, size_t ws_size,
                              hipStream_t stream) {
    const float* x     = (const float*)d_in[0];
    const float* c1w   = (const float*)d_in[1];
    const float* c1b   = (const float*)d_in[2];
    const float* b1g   = (const float*)d_in[3];
    const float* b1b   = (const float*)d_in[4];
    const float* b1m   = (const float*)d_in[5];
    const float* b1v   = (const float*)d_in[6];
    const float* c2w   = (const float*)d_in[7];
    const float* c2b   = (const float*)d_in[8];
    const float* b2g   = (const float*)d_in[9];
    const float* b2b   = (const float*)d_in[10];
    const float* b2m   = (const float*)d_in[11];
    const float* b2v   = (const float*)d_in[12];
    const float* c3w   = (const float*)d_in[13];
    const float* c3b   = (const float*)d_in[14];
    const float* b3g   = (const float*)d_in[15];
    const float* b3b   = (const float*)d_in[16];
    const float* b3m   = (const float*)d_in[17];
    const float* b3v   = (const float*)d_in[18];
    const float* pjw   = (const float*)d_in[19];
    const float* pjb   = (const float*)d_in[20];
    const float* cw    = (const float*)d_in[21];
    const float* cbias = (const float*)d_in[22];
    float* outp = (float*)d_out;

    float* A  = (float*)d_ws;              // h1 [512][16][32][32] then h3 [512][64][8][8]
    float* Bp = A + 8388608;               // h2 [512][32][16][16]
    unsigned char* prep = (unsigned char*)(Bp + 4194304);
    unsigned short* wp2 = (unsigned short*)prep;                     // 5120 bf16
    unsigned short* wp3 = (unsigned short*)(prep + 16384);           // 18432 bf16
    unsigned short* wp1 = (unsigned short*)(prep + 16384 + 36864);   // 1024 bf16
    float* cst2 = (float*)(prep + 16384 + 36864 + 2048);             // 64 floats
    float* cst3 = cst2 + 64;                                         // 128 floats
    float* cst1 = cst3 + 128;                                        // 32 floats

    k_prep<<<97, 256, 0, stream>>>(c2w, c3w, b2g, b2b, b2m, b2v, c2b,
                                   b3g, b3b, b3m, b3v, c3b,
                                   c1w, b1g, b1b, b1m, b1v, c1b,
                                   wp2, wp3, wp1, cst2, cst3, cst1);
    k_conv1m<<<1024, 256, 0, stream>>>(x, wp1, cst1, A);
    k_conv2m<<<1024, 256, 0, stream>>>(A, wp2, cst2, Bp);
    k_conv3m<<<512, 256, 0, stream>>>(Bp, wp3, cst3, A);
    k_head<<<512, 256, 0, stream>>>(A, pjw, pjb, cw, cbias, outp);
}

// Round 6
// 164.516 us; speedup vs baseline: 1.8921x; 1.1384x over previous
//
#include <hip/hip_runtime.h>
#include <hip/hip_bf16.h>
#include <math.h>

typedef __attribute__((ext_vector_type(8))) short short8;
typedef __attribute__((ext_vector_type(4))) float f32x4;

__device__ __forceinline__ unsigned short f2bf(float f) {
    union { float f; unsigned u; } x; x.f = f;
    unsigned r = x.u + 0x7FFF + ((x.u >> 16) & 1);
    return (unsigned short)(r >> 16);
}

__device__ __forceinline__ short8 mk8(uint2 a, uint2 b) {
    union { uint2 u[2]; short8 s; } x;
    x.u[0] = a; x.u[1] = b;
    return x.s;
}

// ---------------- prep: weights -> MFMA A-frag order (bf16); bn consts; pjw transpose
// wp2[s<5][ocT<2][lane<64][j<8]: k=(lane>>4)*8+j -> (tap=s*2+(k>>4), ic=k&15)
// wp3[tap<9][ocT<4][lane<64][j<8]: ic=(lane>>4)*8+j
// wp1[s<2][lane<64][j<8]: s0: k=tap*4+ic (taps 0..7, ic<3 real); s1: k<3 -> ic of tap8
// pjwt[k][d][c] fp32 transposed from pjw[k][c][d]
__global__ void k_prep(const float* __restrict__ w2, const float* __restrict__ w3,
    const float* g2, const float* be2, const float* m2, const float* v2, const float* cb2,
    const float* g3, const float* be3, const float* m3, const float* v3, const float* cb3,
    const float* __restrict__ w1,
    const float* g1, const float* be1, const float* m1, const float* v1, const float* cb1,
    const float* __restrict__ pjw,
    unsigned short* __restrict__ wp2, unsigned short* __restrict__ wp3,
    unsigned short* __restrict__ wp1,
    float* __restrict__ cst2, float* __restrict__ cst3, float* __restrict__ cst1,
    float* __restrict__ pjwt)
{
    int tid = blockIdx.x * 256 + threadIdx.x;
    if (tid < 5120) {
        int j = tid & 7, lane = (tid >> 3) & 63, o = (tid >> 9) & 1, s = tid >> 10;
        int kl = ((lane >> 4) << 3) + j;
        int tp = s * 2 + (kl >> 4);
        int ic = kl & 15;
        int oc = o * 16 + (lane & 15);
        float val = (tp < 9) ? w2[(oc * 16 + ic) * 9 + tp] : 0.f;
        wp2[tid] = f2bf(val);
    } else if (tid < 23552) {
        int idx = tid - 5120;
        int j = idx & 7, lane = (idx >> 3) & 63, o = (idx >> 9) & 3, tap = idx >> 11;
        int ic = ((lane >> 4) << 3) + j;
        int oc = o * 16 + (lane & 15);
        wp3[idx] = f2bf(w3[(oc * 32 + ic) * 9 + tap]);
    } else if (tid < 23648) {
        int c = tid - 23552;
        if (c < 32) {
            float inv = g2[c] * rsqrtf(v2[c] + 1e-5f);
            cst2[c] = inv;
            cst2[32 + c] = (cb2[c] - m2[c]) * inv + be2[c];
        } else {
            int c3 = c - 32;
            float inv = g3[c3] * rsqrtf(v3[c3] + 1e-5f);
            cst3[c3] = inv;
            cst3[64 + c3] = (cb3[c3] - m3[c3]) * inv + be3[c3];
        }
    } else if (tid < 24672) {
        int idx = tid - 23648;
        int j = idx & 7, lane = (idx >> 3) & 63, s = (idx >> 9) & 1;
        int k = ((lane >> 4) << 3) + j;
        int oc = lane & 15;
        float val = 0.f;
        if (s == 0) {
            int tap = k >> 2, ic = k & 3;
            if (ic < 3) val = w1[(oc * 3 + ic) * 9 + tap];
        } else {
            if (k < 3) val = w1[(oc * 3 + k) * 9 + 8];
        }
        wp1[idx] = f2bf(val);
    } else if (tid < 24688) {
        int c = tid - 24672;
        float inv = g1[c] * rsqrtf(v1[c] + 1e-5f);
        cst1[c] = inv;
        cst1[16 + c] = (cb1[c] - m1[c]) * inv + be1[c];
    } else if (tid < 57456) {
        int idx = tid - 24688;
        int k = idx >> 11, d = (idx >> 8) & 7, c = idx & 255;
        pjwt[idx] = pjw[k * 2048 + c * 8 + d];
    }
}

// ---------------- Layer 1 (MFMA): conv 3->16 + bn + relu + pool -> h1 NHWC bf16 [b][32][32][16]
// grid 1024 = (b, half). LDS xs[34 rows][66 x][4 ic] bf16.
__global__ __launch_bounds__(256) void k_conv1m(const float* __restrict__ x,
    const unsigned short* __restrict__ wp, const float* __restrict__ cst,
    unsigned short* __restrict__ out)
{
    __shared__ __align__(16) unsigned short xs[2244 * 4];
    int bid = blockIdx.x;
    int b = bid >> 1, h = bid & 1;
    int t = threadIdx.x;
    const float* img = x + (size_t)b * 3 * 4096;
    int y0 = h * 32 - 1;
    #pragma unroll 1
    for (int i = 0; i < 9; ++i) {
        int idx = t + i * 256;
        if (idx < 2244) {
            int y = idx / 66, xx = idx - y * 66;
            int gy = y0 + y, gx = xx - 1;
            float v0 = 0.f, v1 = 0.f, v2 = 0.f;
            if ((unsigned)gy < 64u && (unsigned)gx < 64u) {
                const float* pb = img + gy * 64 + gx;
                v0 = pb[0]; v1 = pb[4096]; v2 = pb[8192];
            }
            uint2 pk;
            pk.x = (unsigned)f2bf(v0) | ((unsigned)f2bf(v1) << 16);
            pk.y = (unsigned)f2bf(v2);
            ((uint2*)xs)[idx] = pk;
        }
    }
    int lane = t & 63, w = t >> 6;
    int q = lane >> 4, xl = lane & 15;
    short8 A0 = *(const short8*)(wp + (lane << 3));
    short8 A1 = *(const short8*)(wp + ((64 + lane) << 3));
    int t0 = 2 * q, t1 = 2 * q + 1;
    int dy0 = t0 / 3 - 1, dx0 = t0 % 3 - 1;
    int dy1 = t1 / 3 - 1, dx1 = t1 % 3 - 1;
    float invr[4], bsr[4];
    #pragma unroll
    for (int reg = 0; reg < 4; ++reg) {
        int oc = q * 4 + reg;
        invr[reg] = cst[oc]; bsr[reg] = cst[16 + oc];
    }
    __syncthreads();
    #pragma unroll 1
    for (int xT = 0; xT < 4; ++xT) {
        int xb = xT * 16 + xl + 1;
        float pv[4];
        #pragma unroll
        for (int r = 0; r < 8; ++r) {
            int ly = w * 8 + r + 1;
            const uint2* base = (const uint2*)xs;
            uint2 ua = base[(ly + dy0) * 66 + xb + dx0];
            uint2 ub = base[(ly + dy1) * 66 + xb + dx1];
            uint2 uc = base[(ly + 1) * 66 + xb + 1];
            f32x4 acc = (f32x4){0.f, 0.f, 0.f, 0.f};
            acc = __builtin_amdgcn_mfma_f32_16x16x32_bf16(A0, mk8(ua, ub), acc, 0, 0, 0);
            acc = __builtin_amdgcn_mfma_f32_16x16x32_bf16(A1, mk8(uc, uc), acc, 0, 0, 0);
            #pragma unroll
            for (int reg = 0; reg < 4; ++reg) {
                float val = fmaxf(acc[reg] * invr[reg] + bsr[reg], 0.f);
                if (r & 1) {
                    float vm = fmaxf(val, pv[reg]);
                    float vo = fmaxf(vm, __shfl_xor(vm, 1, 64));
                    if (!(lane & 1)) {
                        int oc = q * 4 + reg;
                        int py = h * 16 + w * 4 + (r >> 1);
                        int px = xT * 8 + (xl >> 1);
                        out[(((size_t)b * 32 + py) * 32 + px) * 16 + oc] = f2bf(vo);
                    }
                } else {
                    pv[reg] = val;
                }
            }
        }
    }
}

// ---------------- Layer 2 (MFMA): conv 16->32 + bn + relu + pool -> h2 NHWC bf16 [b][16][16][32]
// grid 1024 = (b, half). LDS x2[612 pos][24 shorts] (16 ic + pad), staging = aligned uint4 copies.
__global__ __launch_bounds__(256) void k_conv2m(const unsigned short* __restrict__ in,
    const unsigned short* __restrict__ wp, const float* __restrict__ cst,
    unsigned short* __restrict__ out)
{
    __shared__ __align__(16) unsigned short x2[612 * 24];   // 29376 B
    int bid = blockIdx.x;
    int b = bid >> 1, h = bid & 1;
    int t = threadIdx.x;
    const unsigned short* src = in + (size_t)b * 16384;
    #pragma unroll 1
    for (int i = 0; i < 5; ++i) {
        int idx = t + i * 256;
        if (idx < 1224) {
            int pos = idx >> 1, half = idx & 1;
            int y = pos / 34, xx = pos - y * 34;
            int gy = h * 16 + y - 1, gx = xx - 1;
            uint4 val = {0u, 0u, 0u, 0u};
            if ((unsigned)gy < 32u && (unsigned)gx < 32u)
                val = *(const uint4*)(src + (gy * 32 + gx) * 16 + half * 8);
            *(uint4*)(x2 + pos * 24 + half * 8) = val;
        }
    }
    int lane = t & 63, w = t >> 6;
    int q = lane >> 4, xl = lane & 15;
    short8 A[5][2];
    #pragma unroll
    for (int s = 0; s < 5; ++s)
        #pragma unroll
        for (int o = 0; o < 2; ++o)
            A[s][o] = *(const short8*)(wp + (((s * 2 + o) * 64 + lane) << 3));
    int dyA[5], dxA[5];
    #pragma unroll
    for (int s = 0; s < 5; ++s) {
        int tp = s * 2 + (q >> 1); if (tp > 8) tp = 8;
        int d3 = tp / 3;
        dyA[s] = d3 - 1; dxA[s] = tp - d3 * 3 - 1;
    }
    __syncthreads();
    f32x4 acc[4][2][2];
    #pragma unroll
    for (int r = 0; r < 4; ++r)
        #pragma unroll
        for (int xT = 0; xT < 2; ++xT)
            #pragma unroll
            for (int o = 0; o < 2; ++o)
                acc[r][xT][o] = (f32x4){0.f, 0.f, 0.f, 0.f};
    #pragma unroll
    for (int r = 0; r < 4; ++r) {
        int ry = w * 4 + r + 1;
        #pragma unroll
        for (int xT = 0; xT < 2; ++xT) {
            int xb = xT * 16 + xl + 1;
            #pragma unroll
            for (int s = 0; s < 5; ++s) {
                int pos = (ry + dyA[s]) * 34 + xb + dxA[s];
                short8 B = *(const short8*)(x2 + pos * 24 + (q & 1) * 8);
                acc[r][xT][0] = __builtin_amdgcn_mfma_f32_16x16x32_bf16(A[s][0], B, acc[r][xT][0], 0, 0, 0);
                acc[r][xT][1] = __builtin_amdgcn_mfma_f32_16x16x32_bf16(A[s][1], B, acc[r][xT][1], 0, 0, 0);
            }
        }
    }
    #pragma unroll
    for (int oT = 0; oT < 2; ++oT) {
        #pragma unroll
        for (int reg = 0; reg < 4; ++reg) {
            int oc = oT * 16 + q * 4 + reg;
            float inv = cst[oc], bs = cst[32 + oc];
            #pragma unroll
            for (int rp = 0; rp < 2; ++rp) {
                #pragma unroll
                for (int xT = 0; xT < 2; ++xT) {
                    float v0 = fmaxf(acc[rp * 2][xT][oT][reg] * inv + bs, 0.f);
                    float v1 = fmaxf(acc[rp * 2 + 1][xT][oT][reg] * inv + bs, 0.f);
                    float vm = fmaxf(v0, v1);
                    float vo = fmaxf(vm, __shfl_xor(vm, 1, 64));
                    if (!(lane & 1)) {
                        int py = h * 8 + w * 2 + rp;
                        int px = xT * 8 + (xl >> 1);
                        out[(((size_t)b * 16 + py) * 16 + px) * 32 + oc] = f2bf(vo);
                    }
                }
            }
        }
    }
}

// ---------------- Layer 3 + head fused: conv 32->64 + bn + relu + pool -> feats (LDS) ->
// projection -> tanh -> analytic quantum map -> classifier. grid 512 = b.
__global__ __launch_bounds__(256) void k_conv3h(const unsigned short* __restrict__ in,
    const unsigned short* __restrict__ wp, const float* __restrict__ cst,
    const float* __restrict__ pjwt, const float* __restrict__ pjb,
    const float* __restrict__ cw, const float* __restrict__ cbias,
    float* __restrict__ out)
{
    __shared__ __align__(16) unsigned short x3[324 * 40];   // 25920 B
    __shared__ __align__(16) float feats[64][68];           // 17408 B (padded rows)
    __shared__ float czs[16][8];
    __shared__ float part[16][10];
    int b = blockIdx.x;
    int t = threadIdx.x;
    const unsigned short* src = in + (size_t)b * 8192;
    #pragma unroll 1
    for (int i = 0; i < 6; ++i) {
        int idx = t + i * 256;
        if (idx < 1296) {
            int pos = idx >> 2, qt = idx & 3;
            int y = pos / 18, xx = pos - y * 18;
            int gy = y - 1, gx = xx - 1;
            uint4 val = {0u, 0u, 0u, 0u};
            if ((unsigned)gy < 16u && (unsigned)gx < 16u)
                val = *(const uint4*)(src + (gy * 16 + gx) * 32 + qt * 8);
            *(uint4*)(x3 + pos * 40 + qt * 8) = val;
        }
    }
    __syncthreads();
    int lane = t & 63, w = t >> 6;
    int q = lane >> 4, xl = lane & 15;
    #pragma unroll 1
    for (int op = 0; op < 2; ++op) {
        short8 A[9][2];
        #pragma unroll
        for (int tap = 0; tap < 9; ++tap)
            #pragma unroll
            for (int tt = 0; tt < 2; ++tt)
                A[tap][tt] = *(const short8*)(wp + (((tap * 4 + op * 2 + tt) * 64 + lane) << 3));
        f32x4 acc[4][2];
        #pragma unroll
        for (int r = 0; r < 4; ++r) {
            acc[r][0] = (f32x4){0.f, 0.f, 0.f, 0.f};
            acc[r][1] = (f32x4){0.f, 0.f, 0.f, 0.f};
        }
        #pragma unroll
        for (int r = 0; r < 4; ++r) {
            int ry = w * 4 + r + 1;
            #pragma unroll
            for (int tap = 0; tap < 9; ++tap) {
                int pos = (ry + tap / 3 - 1) * 18 + xl + (tap % 3);
                short8 B = *(const short8*)(x3 + pos * 40 + q * 8);
                acc[r][0] = __builtin_amdgcn_mfma_f32_16x16x32_bf16(A[tap][0], B, acc[r][0], 0, 0, 0);
                acc[r][1] = __builtin_amdgcn_mfma_f32_16x16x32_bf16(A[tap][1], B, acc[r][1], 0, 0, 0);
            }
        }
        #pragma unroll
        for (int tt = 0; tt < 2; ++tt) {
            #pragma unroll
            for (int reg = 0; reg < 4; ++reg) {
                int oc = (op * 2 + tt) * 16 + q * 4 + reg;
                float inv = cst[oc], bs = cst[64 + oc];
                #pragma unroll
                for (int rp = 0; rp < 2; ++rp) {
                    float v0 = fmaxf(acc[rp * 2][tt][reg] * inv + bs, 0.f);
                    float v1 = fmaxf(acc[rp * 2 + 1][tt][reg] * inv + bs, 0.f);
                    float vm = fmaxf(v0, v1);
                    float vo = fmaxf(vm, __shfl_xor(vm, 1, 64));
                    if (!(lane & 1))
                        feats[oc][(w * 2 + rp) * 8 + (xl >> 1)] = vo;
                }
            }
        }
    }
    __syncthreads();
    // projection: one lane per (k,d); feats(k,c) = feats[k*4 + (c>>6)][c&63]
    if (t < 128) {
        int k = t >> 3, d = t & 7;
        const float4* wrow = (const float4*)(pjwt + (k * 8 + d) * 256);
        float zacc = 0.f;
        #pragma unroll 4
        for (int c4 = 0; c4 < 64; ++c4) {
            float4 wv = wrow[c4];
            float4 fv = *(const float4*)(&feats[k * 4 + (c4 >> 4)][4 * (c4 & 15)]);
            zacc = fmaf(wv.x, fv.x, zacc);
            zacc = fmaf(wv.y, fv.y, zacc);
            zacc = fmaf(wv.z, fv.z, zacc);
            zacc = fmaf(wv.w, fv.w, zacc);
        }
        float z = zacc + pjb[k * 8 + d];
        czs[k][d] = cosf(0.5f * tanhf(z));
    }
    __syncthreads();
    // classifier: single[i]=prod_{q<=i}cz; pair(i,j)=prod_{i<q<=j}cz
    if (t < 160) {
        int k = t / 10, c = t - (t / 10) * 10;
        float cz[8];
        #pragma unroll
        for (int i = 0; i < 8; ++i) cz[i] = czs[k][i];
        const float* cwp = cw + c * 576 + k * 36;
        float s = 0.f;
        float pp = 1.f;
        #pragma unroll
        for (int i = 0; i < 8; ++i) { pp *= cz[i]; s = fmaf(pp, cwp[i], s); }
        int cnt = 8;
        #pragma unroll
        for (int i = 0; i < 8; ++i) {
            float p2 = 1.f;
            #pragma unroll
            for (int j = i + 1; j < 8; ++j) { p2 *= cz[j]; s = fmaf(p2, cwp[cnt++], s); }
        }
        part[k][c] = s;
    }
    __syncthreads();
    if (t < 10) {
        float s = cbias[t];
        #pragma unroll
        for (int k = 0; k < 16; ++k) s += part[k][t];
        out[b * 10 + t] = s;
    }
}

extern "C" void kernel_launch(void* const* d_in, const int* in_sizes, int n_in,
                              void* d_out, int out_size, void* d_ws, size_t ws_size,
                              hipStream_t stream) {
    const float* x     = (const float*)d_in[0];
    const float* c1w   = (const float*)d_in[1];
    const float* c1b   = (const float*)d_in[2];
    const float* b1g   = (const float*)d_in[3];
    const float* b1b   = (const float*)d_in[4];
    const float* b1m   = (const float*)d_in[5];
    const float* b1v   = (const float*)d_in[6];
    const float* c2w   = (const float*)d_in[7];
    const float* c2b   = (const float*)d_in[8];
    const float* b2g   = (const float*)d_in[9];
    const float* b2b   = (const float*)d_in[10];
    const float* b2m   = (const float*)d_in[11];
    const float* b2v   = (const float*)d_in[12];
    const float* c3w   = (const float*)d_in[13];
    const float* c3b   = (const float*)d_in[14];
    const float* b3g   = (const float*)d_in[15];
    const float* b3b   = (const float*)d_in[16];
    const float* b3m   = (const float*)d_in[17];
    const float* b3v   = (const float*)d_in[18];
    const float* pjw   = (const float*)d_in[19];
    const float* pjb   = (const float*)d_in[20];
    const float* cw    = (const float*)d_in[21];
    const float* cbias = (const float*)d_in[22];
    float* outp = (float*)d_out;

    unsigned short* h1 = (unsigned short*)d_ws;      // NHWC bf16 [512][32][32][16]
    unsigned short* h2 = h1 + 8388608;               // NHWC bf16 [512][16][16][32]
    unsigned char* prep = (unsigned char*)(h2 + 4194304);
    unsigned short* wp2 = (unsigned short*)prep;                       // 5120 bf16
    unsigned short* wp3 = (unsigned short*)(prep + 16384);             // 18432 bf16
    unsigned short* wp1 = (unsigned short*)(prep + 16384 + 36864);     // 1024 bf16
    float* cst2 = (float*)(prep + 16384 + 36864 + 2048);               // 64 f
    float* cst3 = cst2 + 64;                                           // 128 f
    float* cst1 = cst3 + 128;                                          // 32 f
    float* pjwt = (float*)(prep + 16384 + 36864 + 2048 + 1024);        // 32768 f

    k_prep<<<225, 256, 0, stream>>>(c2w, c3w, b2g, b2b, b2m, b2v, c2b,
                                    b3g, b3b, b3m, b3v, c3b,
                                    c1w, b1g, b1b, b1m, b1v, c1b, pjw,
                                    wp2, wp3, wp1, cst2, cst3, cst1, pjwt);
    k_conv1m<<<1024, 256, 0, stream>>>(x, wp1, cst1, h1);
    k_conv2m<<<1024, 256, 0, stream>>>(h1, wp2, cst2, h2);
    k_conv3h<<<512, 256, 0, stream>>>(h2, wp3, cst3, pjwt, pjb, cw, cbias, outp);
}

// Round 7
// 147.108 us; speedup vs baseline: 2.1160x; 1.1183x over previous
//
#include <hip/hip_runtime.h>
#include <hip/hip_bf16.h>
#include <math.h>

typedef __attribute__((ext_vector_type(8))) short short8;
typedef __attribute__((ext_vector_type(4))) float f32x4;

__device__ __forceinline__ unsigned short f2bf(float f) {
    union { float f; unsigned u; } x; x.f = f;
    unsigned r = x.u + 0x7FFF + ((x.u >> 16) & 1);
    return (unsigned short)(r >> 16);
}

__device__ __forceinline__ short8 mk8(uint2 a, uint2 b) {
    union { uint2 u[2]; short8 s; } x;
    x.u[0] = a; x.u[1] = b;
    return x.s;
}

__device__ __forceinline__ short8 mk8u(unsigned a, unsigned b, unsigned c, unsigned d) {
    union { unsigned u[4]; short8 s; } x;
    x.u[0] = a; x.u[1] = b; x.u[2] = c; x.u[3] = d;
    return x.s;
}

// ---------------- prep: weights -> MFMA A-frag order (bf16); bn consts; pjw transpose
__global__ void k_prep(const float* __restrict__ w2, const float* __restrict__ w3,
    const float* g2, const float* be2, const float* m2, const float* v2, const float* cb2,
    const float* g3, const float* be3, const float* m3, const float* v3, const float* cb3,
    const float* __restrict__ w1,
    const float* g1, const float* be1, const float* m1, const float* v1, const float* cb1,
    const float* __restrict__ pjw,
    unsigned short* __restrict__ wp2, unsigned short* __restrict__ wp3,
    unsigned short* __restrict__ wp1,
    float* __restrict__ cst2, float* __restrict__ cst3, float* __restrict__ cst1,
    float* __restrict__ pjwt)
{
    int tid = blockIdx.x * 256 + threadIdx.x;
    if (tid < 5120) {
        int j = tid & 7, lane = (tid >> 3) & 63, o = (tid >> 9) & 1, s = tid >> 10;
        int kl = ((lane >> 4) << 3) + j;
        int tp = s * 2 + (kl >> 4);
        int ic = kl & 15;
        int oc = o * 16 + (lane & 15);
        float val = (tp < 9) ? w2[(oc * 16 + ic) * 9 + tp] : 0.f;
        wp2[tid] = f2bf(val);
    } else if (tid < 23552) {
        int idx = tid - 5120;
        int j = idx & 7, lane = (idx >> 3) & 63, o = (idx >> 9) & 3, tap = idx >> 11;
        int ic = ((lane >> 4) << 3) + j;
        int oc = o * 16 + (lane & 15);
        wp3[idx] = f2bf(w3[(oc * 32 + ic) * 9 + tap]);
    } else if (tid < 23648) {
        int c = tid - 23552;
        if (c < 32) {
            float inv = g2[c] * rsqrtf(v2[c] + 1e-5f);
            cst2[c] = inv;
            cst2[32 + c] = (cb2[c] - m2[c]) * inv + be2[c];
        } else {
            int c3 = c - 32;
            float inv = g3[c3] * rsqrtf(v3[c3] + 1e-5f);
            cst3[c3] = inv;
            cst3[64 + c3] = (cb3[c3] - m3[c3]) * inv + be3[c3];
        }
    } else if (tid < 24672) {
        int idx = tid - 23648;
        int j = idx & 7, lane = (idx >> 3) & 63, s = (idx >> 9) & 1;
        int k = ((lane >> 4) << 3) + j;
        int oc = lane & 15;
        float val = 0.f;
        if (s == 0) {
            int tap = k >> 2, ic = k & 3;
            if (ic < 3) val = w1[(oc * 3 + ic) * 9 + tap];
        } else {
            if (k < 3) val = w1[(oc * 3 + k) * 9 + 8];
        }
        wp1[idx] = f2bf(val);
    } else if (tid < 24688) {
        int c = tid - 24672;
        float inv = g1[c] * rsqrtf(v1[c] + 1e-5f);
        cst1[c] = inv;
        cst1[16 + c] = (cb1[c] - m1[c]) * inv + be1[c];
    } else if (tid < 57456) {
        int idx = tid - 24688;
        int k = idx >> 11, d = (idx >> 8) & 7, c = idx & 255;
        pjwt[idx] = pjw[k * 2048 + c * 8 + d];
    }
}

// ---------------- Fused: conv1+conv2+conv3+head, one block per image.
// LDS union (62784 B, 2 blocks/CU):
//  region0 [0,25920):   xs half-tile [34][66][4] bf16 (17952B)  |  h2t [18][18][40] bf16 (25920B, bordered)
//  region1 [25920,62784): h1 [32][32][18] bf16 (36864B, stride 18 -> conflict-free)
//                          | feats [64][68] f32 (17408B) + czs(512B) + part(640B)
__global__ __launch_bounds__(256, 2) void k_fused(
    const float* __restrict__ x,
    const unsigned short* __restrict__ wp1, const float* __restrict__ cst1,
    const unsigned short* __restrict__ wp2, const float* __restrict__ cst2,
    const unsigned short* __restrict__ wp3, const float* __restrict__ cst3,
    const float* __restrict__ pjwt, const float* __restrict__ pjb,
    const float* __restrict__ cw, const float* __restrict__ cbias,
    float* __restrict__ out)
{
    __shared__ __align__(16) unsigned char smem[62784];
    unsigned short* xs  = (unsigned short*)smem;             // conv1 staging
    unsigned short* h2t = (unsigned short*)smem;             // conv2 output (bordered)
    unsigned short* h1  = (unsigned short*)(smem + 25920);   // conv1 output
    float* feats = (float*)(smem + 25920);                   // conv3 output
    float* czs   = (float*)(smem + 25920 + 17408);
    float* partl = czs + 128;

    int b = blockIdx.x, t = threadIdx.x;
    int lane = t & 63, w = t >> 6, q = lane >> 4, xl = lane & 15;
    const float* img = x + (size_t)b * 12288;

    // ======== conv1: 3->16, 64x64, pool -> h1 [32][32][16] (stride 18) ========
    short8 A10 = *(const short8*)(wp1 + (lane << 3));
    short8 A11 = *(const short8*)(wp1 + ((64 + lane) << 3));
    int t0 = 2 * q, t1 = 2 * q + 1;
    int dy0 = t0 / 3 - 1, dx0 = t0 % 3 - 1;
    int dy1 = t1 / 3 - 1, dx1 = t1 % 3 - 1;
    float inv1[4], bs1[4];
    #pragma unroll
    for (int reg = 0; reg < 4; ++reg) {
        inv1[reg] = cst1[q * 4 + reg];
        bs1[reg]  = cst1[16 + q * 4 + reg];
    }
    #pragma unroll 1
    for (int h = 0; h < 2; ++h) {
        if (h) __syncthreads();
        int y0 = h * 32 - 1;
        #pragma unroll 1
        for (int i = 0; i < 9; ++i) {
            int idx = t + i * 256;
            if (idx < 2244) {
                int y = idx / 66, xx = idx - y * 66;
                int gy = y0 + y, gx = xx - 1;
                float v0 = 0.f, v1 = 0.f, v2 = 0.f;
                if ((unsigned)gy < 64u && (unsigned)gx < 64u) {
                    const float* pb = img + gy * 64 + gx;
                    v0 = pb[0]; v1 = pb[4096]; v2 = pb[8192];
                }
                uint2 pk;
                pk.x = (unsigned)f2bf(v0) | ((unsigned)f2bf(v1) << 16);
                pk.y = (unsigned)f2bf(v2);
                ((uint2*)xs)[idx] = pk;
            }
        }
        __syncthreads();
        #pragma unroll 1
        for (int xT = 0; xT < 4; ++xT) {
            int xb = xT * 16 + xl + 1;
            float pv[4], vo[4];
            #pragma unroll
            for (int r = 0; r < 8; ++r) {
                int ly = w * 8 + r + 1;
                const uint2* base = (const uint2*)xs;
                uint2 ua = base[(ly + dy0) * 66 + xb + dx0];
                uint2 ub = base[(ly + dy1) * 66 + xb + dx1];
                uint2 uc = base[(ly + 1) * 66 + xb + 1];
                f32x4 acc = (f32x4){0.f, 0.f, 0.f, 0.f};
                acc = __builtin_amdgcn_mfma_f32_16x16x32_bf16(A10, mk8(ua, ub), acc, 0, 0, 0);
                acc = __builtin_amdgcn_mfma_f32_16x16x32_bf16(A11, mk8(uc, uc), acc, 0, 0, 0);
                #pragma unroll
                for (int reg = 0; reg < 4; ++reg) {
                    float val = fmaxf(acc[reg] * inv1[reg] + bs1[reg], 0.f);
                    if (r & 1) {
                        float vm = fmaxf(val, pv[reg]);
                        vo[reg] = fmaxf(vm, __shfl_xor(vm, 1, 64));
                    } else {
                        pv[reg] = val;
                    }
                }
                if ((r & 1) && !(lane & 1)) {
                    int py = h * 16 + w * 4 + (r >> 1);
                    int px = xT * 8 + (xl >> 1);
                    int pos = py * 32 + px;
                    unsigned u0 = (unsigned)f2bf(vo[0]) | ((unsigned)f2bf(vo[1]) << 16);
                    unsigned u1 = (unsigned)f2bf(vo[2]) | ((unsigned)f2bf(vo[3]) << 16);
                    unsigned* hp = (unsigned*)h1 + pos * 9 + q * 2;
                    hp[0] = u0; hp[1] = u1;
                }
            }
        }
    }
    __syncthreads();

    // ======== conv2: 16->32, 32x32, pool -> h2t [18][18][32] (bordered, stride 40) ========
    if (t < 68) {   // zero h2t border
        int y, xx;
        if (t < 18)      { y = 0;       xx = t; }
        else if (t < 36) { y = 17;      xx = t - 18; }
        else if (t < 52) { y = t - 35;  xx = 0; }
        else             { y = t - 51;  xx = 17; }
        uint4* p = (uint4*)(h2t + (y * 18 + xx) * 40);
        uint4 z = {0u, 0u, 0u, 0u};
        p[0] = z; p[1] = z; p[2] = z; p[3] = z; p[4] = z;
    }
    short8 A2[5][2];
    #pragma unroll
    for (int s = 0; s < 5; ++s)
        #pragma unroll
        for (int o = 0; o < 2; ++o)
            A2[s][o] = *(const short8*)(wp2 + (((s * 2 + o) * 64 + lane) << 3));
    int dyA[5], dxA[5];
    #pragma unroll
    for (int s = 0; s < 5; ++s) {
        int tp = s * 2 + (q >> 1); if (tp > 8) tp = 8;
        int d3 = tp / 3;
        dyA[s] = d3 - 1; dxA[s] = tp - d3 * 3 - 1;
    }
    #pragma unroll 1
    for (int rr = 0; rr < 2; ++rr) {
        f32x4 acc[4][2][2];
        #pragma unroll
        for (int r = 0; r < 4; ++r)
            #pragma unroll
            for (int xT = 0; xT < 2; ++xT)
                #pragma unroll
                for (int o = 0; o < 2; ++o)
                    acc[r][xT][o] = (f32x4){0.f, 0.f, 0.f, 0.f};
        #pragma unroll
        for (int r = 0; r < 4; ++r) {
            int ry = w * 8 + rr * 4 + r;
            #pragma unroll
            for (int xT = 0; xT < 2; ++xT) {
                int gxb = xT * 16 + xl;
                #pragma unroll
                for (int s = 0; s < 5; ++s) {
                    int gy = ry + dyA[s], gx = gxb + dxA[s];
                    bool ok = ((unsigned)gy < 32u) && ((unsigned)gx < 32u);
                    int pos = ok ? gy * 32 + gx : 0;
                    const unsigned* hp = (const unsigned*)h1 + pos * 9 + (q & 1) * 4;
                    unsigned u0 = hp[0], u1 = hp[1], u2 = hp[2], u3 = hp[3];
                    if (!ok) { u0 = 0; u1 = 0; u2 = 0; u3 = 0; }
                    short8 B = mk8u(u0, u1, u2, u3);
                    acc[r][xT][0] = __builtin_amdgcn_mfma_f32_16x16x32_bf16(A2[s][0], B, acc[r][xT][0], 0, 0, 0);
                    acc[r][xT][1] = __builtin_amdgcn_mfma_f32_16x16x32_bf16(A2[s][1], B, acc[r][xT][1], 0, 0, 0);
                }
            }
        }
        #pragma unroll
        for (int oT = 0; oT < 2; ++oT)
            #pragma unroll
            for (int rp = 0; rp < 2; ++rp)
                #pragma unroll
                for (int xT = 0; xT < 2; ++xT) {
                    float vo[4];
                    #pragma unroll
                    for (int reg = 0; reg < 4; ++reg) {
                        int oc = oT * 16 + q * 4 + reg;
                        float inv = cst2[oc], bs = cst2[32 + oc];
                        float v0 = fmaxf(acc[rp * 2][xT][oT][reg] * inv + bs, 0.f);
                        float v1 = fmaxf(acc[rp * 2 + 1][xT][oT][reg] * inv + bs, 0.f);
                        float vm = fmaxf(v0, v1);
                        vo[reg] = fmaxf(vm, __shfl_xor(vm, 1, 64));
                    }
                    if (!(lane & 1)) {
                        int py = w * 4 + rr * 2 + rp;
                        int px = xT * 8 + (xl >> 1);
                        int pos = (py + 1) * 18 + (px + 1);
                        unsigned u0 = (unsigned)f2bf(vo[0]) | ((unsigned)f2bf(vo[1]) << 16);
                        unsigned u1 = (unsigned)f2bf(vo[2]) | ((unsigned)f2bf(vo[3]) << 16);
                        unsigned* hp = (unsigned*)h2t + pos * 20 + oT * 8 + q * 2;
                        hp[0] = u0; hp[1] = u1;
                    }
                }
    }
    __syncthreads();

    // ======== conv3: 32->64, 16x16, pool -> feats [64][68] f32 ========
    #pragma unroll 1
    for (int op = 0; op < 2; ++op) {
        short8 A3[9][2];
        #pragma unroll
        for (int tap = 0; tap < 9; ++tap)
            #pragma unroll
            for (int tt = 0; tt < 2; ++tt)
                A3[tap][tt] = *(const short8*)(wp3 + (((tap * 4 + op * 2 + tt) * 64 + lane) << 3));
        f32x4 acc[4][2];
        #pragma unroll
        for (int r = 0; r < 4; ++r) {
            acc[r][0] = (f32x4){0.f, 0.f, 0.f, 0.f};
            acc[r][1] = (f32x4){0.f, 0.f, 0.f, 0.f};
        }
        #pragma unroll
        for (int r = 0; r < 4; ++r) {
            int ry = w * 4 + r + 1;
            #pragma unroll
            for (int tap = 0; tap < 9; ++tap) {
                int pos = (ry + tap / 3 - 1) * 18 + xl + (tap % 3);
                short8 B = *(const short8*)(h2t + pos * 40 + q * 8);
                acc[r][0] = __builtin_amdgcn_mfma_f32_16x16x32_bf16(A3[tap][0], B, acc[r][0], 0, 0, 0);
                acc[r][1] = __builtin_amdgcn_mfma_f32_16x16x32_bf16(A3[tap][1], B, acc[r][1], 0, 0, 0);
            }
        }
        #pragma unroll
        for (int tt = 0; tt < 2; ++tt)
            #pragma unroll
            for (int reg = 0; reg < 4; ++reg) {
                int oc = (op * 2 + tt) * 16 + q * 4 + reg;
                float inv = cst3[oc], bs = cst3[64 + oc];
                #pragma unroll
                for (int rp = 0; rp < 2; ++rp) {
                    float v0 = fmaxf(acc[rp * 2][tt][reg] * inv + bs, 0.f);
                    float v1 = fmaxf(acc[rp * 2 + 1][tt][reg] * inv + bs, 0.f);
                    float vm = fmaxf(v0, v1);
                    float vv = fmaxf(vm, __shfl_xor(vm, 1, 64));
                    if (!(lane & 1))
                        feats[oc * 68 + (w * 2 + rp) * 8 + (xl >> 1)] = vv;
                }
            }
    }
    __syncthreads();

    // ======== head: projection + tanh + analytic quantum map + classifier ========
    if (t < 128) {
        int k = t >> 3, d = t & 7;
        const float4* wrow = (const float4*)(pjwt + (k * 8 + d) * 256);
        float zacc = 0.f;
        #pragma unroll 4
        for (int i = 0; i < 64; ++i) {
            int c4 = (i + k) & 63;   // rotate start: breaks LDS bank collisions across k
            float4 wv = wrow[c4];
            const float* fp = &feats[(k * 4 + (c4 >> 4)) * 68 + 4 * (c4 & 15)];
            float4 fv = *(const float4*)fp;
            zacc = fmaf(wv.x, fv.x, zacc);
            zacc = fmaf(wv.y, fv.y, zacc);
            zacc = fmaf(wv.z, fv.z, zacc);
            zacc = fmaf(wv.w, fv.w, zacc);
        }
        float z = zacc + pjb[k * 8 + d];
        czs[k * 8 + d] = cosf(0.5f * tanhf(z));
    }
    __syncthreads();
    if (t < 160) {
        int k = t / 10, c = t - (t / 10) * 10;
        float cz[8];
        #pragma unroll
        for (int i = 0; i < 8; ++i) cz[i] = czs[k * 8 + i];
        const float* cwp = cw + c * 576 + k * 36;
        float s = 0.f;
        float pp = 1.f;
        #pragma unroll
        for (int i = 0; i < 8; ++i) { pp *= cz[i]; s = fmaf(pp, cwp[i], s); }
        int cnt = 8;
        #pragma unroll
        for (int i = 0; i < 8; ++i) {
            float p2 = 1.f;
            #pragma unroll
            for (int j = i + 1; j < 8; ++j) { p2 *= cz[j]; s = fmaf(p2, cwp[cnt++], s); }
        }
        partl[k * 10 + c] = s;
    }
    __syncthreads();
    if (t < 10) {
        float s = cbias[t];
        #pragma unroll
        for (int k = 0; k < 16; ++k) s += partl[k * 10 + t];
        out[b * 10 + t] = s;
    }
}

extern "C" void kernel_launch(void* const* d_in, const int* in_sizes, int n_in,
                              void* d_out, int out_size, void* d_ws, size_t ws_size,
                              hipStream_t stream) {
    const float* x     = (const float*)d_in[0];
    const float* c1w   = (const float*)d_in[1];
    const float* c1b   = (const float*)d_in[2];
    const float* b1g   = (const float*)d_in[3];
    const float* b1b   = (const float*)d_in[4];
    const float* b1m   = (const float*)d_in[5];
    const float* b1v   = (const float*)d_in[6];
    const float* c2w   = (const float*)d_in[7];
    const float* c2b   = (const float*)d_in[8];
    const float* b2g   = (const float*)d_in[9];
    const float* b2b   = (const float*)d_in[10];
    const float* b2m   = (const float*)d_in[11];
    const float* b2v   = (const float*)d_in[12];
    const float* c3w   = (const float*)d_in[13];
    const float* c3b   = (const float*)d_in[14];
    const float* b3g   = (const float*)d_in[15];
    const float* b3b   = (const float*)d_in[16];
    const float* b3m   = (const float*)d_in[17];
    const float* b3v   = (const float*)d_in[18];
    const float* pjw   = (const float*)d_in[19];
    const float* pjb   = (const float*)d_in[20];
    const float* cw    = (const float*)d_in[21];
    const float* cbias = (const float*)d_in[22];
    float* outp = (float*)d_out;

    unsigned char* prep = (unsigned char*)d_ws;
    unsigned short* wp2 = (unsigned short*)prep;                       // 5120 bf16
    unsigned short* wp3 = (unsigned short*)(prep + 16384);             // 18432 bf16
    unsigned short* wp1 = (unsigned short*)(prep + 16384 + 36864);     // 1024 bf16
    float* cst2 = (float*)(prep + 16384 + 36864 + 2048);               // 64 f
    float* cst3 = cst2 + 64;                                           // 128 f
    float* cst1 = cst3 + 128;                                          // 32 f
    float* pjwt = (float*)(prep + 16384 + 36864 + 2048 + 1024);        // 32768 f

    k_prep<<<225, 256, 0, stream>>>(c2w, c3w, b2g, b2b, b2m, b2v, c2b,
                                    b3g, b3b, b3m, b3v, c3b,
                                    c1w, b1g, b1b, b1m, b1v, c1b, pjw,
                                    wp2, wp3, wp1, cst2, cst3, cst1, pjwt);
    k_fused<<<512, 256, 0, stream>>>(x, wp1, cst1, wp2, cst2, wp3, cst3,
                                     pjwt, pjb, cw, cbias, outp);
}

// Round 8
// 138.759 us; speedup vs baseline: 2.2433x; 1.0602x over previous
//
#include <hip/hip_runtime.h>
#include <hip/hip_bf16.h>
#include <math.h>

typedef __attribute__((ext_vector_type(8))) short short8;
typedef __attribute__((ext_vector_type(4))) float f32x4;

__device__ __forceinline__ unsigned short f2bf(float f) {
    union { float f; unsigned u; } x; x.f = f;
    unsigned r = x.u + 0x7FFF + ((x.u >> 16) & 1);
    return (unsigned short)(r >> 16);
}

__device__ __forceinline__ short8 mk8(uint2 a, uint2 b) {
    union { uint2 u[2]; short8 s; } x;
    x.u[0] = a; x.u[1] = b;
    return x.s;
}

// ---------------- prep: weights -> MFMA A-frag order (bf16); bn consts; pjw transpose
__global__ void k_prep(const float* __restrict__ w2, const float* __restrict__ w3,
    const float* g2, const float* be2, const float* m2, const float* v2, const float* cb2,
    const float* g3, const float* be3, const float* m3, const float* v3, const float* cb3,
    const float* __restrict__ w1,
    const float* g1, const float* be1, const float* m1, const float* v1, const float* cb1,
    const float* __restrict__ pjw,
    unsigned short* __restrict__ wp2, unsigned short* __restrict__ wp3,
    unsigned short* __restrict__ wp1,
    float* __restrict__ cst2, float* __restrict__ cst3, float* __restrict__ cst1,
    float* __restrict__ pjwt)
{
    int tid = blockIdx.x * 256 + threadIdx.x;
    if (tid < 5120) {
        int j = tid & 7, lane = (tid >> 3) & 63, o = (tid >> 9) & 1, s = tid >> 10;
        int kl = ((lane >> 4) << 3) + j;
        int tp = s * 2 + (kl >> 4);
        int ic = kl & 15;
        int oc = o * 16 + (lane & 15);
        float val = (tp < 9) ? w2[(oc * 16 + ic) * 9 + tp] : 0.f;
        wp2[tid] = f2bf(val);
    } else if (tid < 23552) {
        int idx = tid - 5120;
        int j = idx & 7, lane = (idx >> 3) & 63, o = (idx >> 9) & 3, tap = idx >> 11;
        int ic = ((lane >> 4) << 3) + j;
        int oc = o * 16 + (lane & 15);
        wp3[idx] = f2bf(w3[(oc * 32 + ic) * 9 + tap]);
    } else if (tid < 23648) {
        int c = tid - 23552;
        if (c < 32) {
            float inv = g2[c] * rsqrtf(v2[c] + 1e-5f);
            cst2[c] = inv;
            cst2[32 + c] = (cb2[c] - m2[c]) * inv + be2[c];
        } else {
            int c3 = c - 32;
            float inv = g3[c3] * rsqrtf(v3[c3] + 1e-5f);
            cst3[c3] = inv;
            cst3[64 + c3] = (cb3[c3] - m3[c3]) * inv + be3[c3];
        }
    } else if (tid < 24672) {
        int idx = tid - 23648;
        int j = idx & 7, lane = (idx >> 3) & 63, s = (idx >> 9) & 1;
        int k = ((lane >> 4) << 3) + j;
        int oc = lane & 15;
        float val = 0.f;
        if (s == 0) {
            int tap = k >> 2, ic = k & 3;
            if (ic < 3) val = w1[(oc * 3 + ic) * 9 + tap];
        } else {
            if (k < 3) val = w1[(oc * 3 + k) * 9 + 8];
        }
        wp1[idx] = f2bf(val);
    } else if (tid < 24688) {
        int c = tid - 24672;
        float inv = g1[c] * rsqrtf(v1[c] + 1e-5f);
        cst1[c] = inv;
        cst1[16 + c] = (cb1[c] - m1[c]) * inv + be1[c];
    } else if (tid < 57456) {
        int idx = tid - 24688;
        int k = idx >> 11, d = (idx >> 8) & 7, c = idx & 255;
        pjwt[idx] = pjw[k * 2048 + c * 8 + d];
    }
}

// ---------------- Fused: conv1+conv2+conv3+head, one block (512 thr, 8 waves) per image.
// LDS (57728 B, 2 blocks/CU):
//  region0 [0,20736):  xs [34][66][4ic] bf16 (17952B)  |  h2tA/h2tB [18*18][16] bf16 (2x10368B)
//  region1 [20736,57728): h1A/h1B [34*34][8] bf16 bordered (2x18496B)
//                          | feats [64][68] f32 (17408B) + czs(512B) + part(640B)
__global__ __launch_bounds__(512, 4) void k_fused(
    const float* __restrict__ x,
    const unsigned short* __restrict__ wp1, const float* __restrict__ cst1,
    const unsigned short* __restrict__ wp2, const float* __restrict__ cst2,
    const unsigned short* __restrict__ wp3, const float* __restrict__ cst3,
    const float* __restrict__ pjwt, const float* __restrict__ pjb,
    const float* __restrict__ cw, const float* __restrict__ cbias,
    float* __restrict__ out)
{
    __shared__ __align__(16) unsigned char smem[57728];
    unsigned short* xs   = (unsigned short*)smem;
    unsigned short* h2tA = (unsigned short*)smem;
    unsigned short* h2tB = (unsigned short*)(smem + 10368);
    unsigned short* h1A  = (unsigned short*)(smem + 20736);
    unsigned short* h1B  = (unsigned short*)(smem + 39232);
    float* feats = (float*)(smem + 20736);
    float* czs   = (float*)(smem + 20736 + 17408);
    float* partl = czs + 128;

    int b = blockIdx.x, t = threadIdx.x;
    int lane = t & 63, w = t >> 6, q = lane >> 4, xl = lane & 15;
    const float* img = x + (size_t)b * 12288;

    // zero h1 border (134 pos x 16B x 2 arrays); disjoint from conv1 interior writes
    if (t < 264) {
        int arr = t & 1, idx = t >> 1;
        int y, xx;
        if (idx < 34)       { y = 0;        xx = idx; }
        else if (idx < 68)  { y = 33;       xx = idx - 34; }
        else if (idx < 100) { y = idx - 67; xx = 0; }
        else                { y = idx - 99; xx = 33; }
        uint4 z = {0u, 0u, 0u, 0u};
        *(uint4*)((arr ? h1B : h1A) + (y * 34 + xx) * 8) = z;
    }

    // ======== conv1: 3->16, 64x64, pool -> h1 bordered [34][34][16ic] (split 8+8) ========
    short8 A10 = *(const short8*)(wp1 + (lane << 3));
    short8 A11 = *(const short8*)(wp1 + ((64 + lane) << 3));
    int t0 = 2 * q, t1 = 2 * q + 1;
    int dy0 = t0 / 3 - 1, dx0 = t0 % 3 - 1;
    int dy1 = t1 / 3 - 1, dx1 = t1 % 3 - 1;
    float inv1[4], bs1[4];
    #pragma unroll
    for (int reg = 0; reg < 4; ++reg) {
        inv1[reg] = cst1[q * 4 + reg];
        bs1[reg]  = cst1[16 + q * 4 + reg];
    }
    unsigned* h1w = (unsigned*)(q < 2 ? h1A : h1B);
    #pragma unroll 1
    for (int h = 0; h < 2; ++h) {
        if (h) __syncthreads();
        int y0 = h * 32 - 1;
        #pragma unroll 1
        for (int i = 0; i < 5; ++i) {
            int idx = t + i * 512;
            if (idx < 2244) {
                int y = idx / 66, xx = idx - y * 66;
                int gy = y0 + y, gx = xx - 1;
                float v0 = 0.f, v1 = 0.f, v2 = 0.f;
                if ((unsigned)gy < 64u && (unsigned)gx < 64u) {
                    const float* pb = img + gy * 64 + gx;
                    v0 = pb[0]; v1 = pb[4096]; v2 = pb[8192];
                }
                uint2 pk;
                pk.x = (unsigned)f2bf(v0) | ((unsigned)f2bf(v1) << 16);
                pk.y = (unsigned)f2bf(v2);
                ((uint2*)xs)[idx] = pk;
            }
        }
        __syncthreads();
        #pragma unroll 1
        for (int xT = 0; xT < 4; ++xT) {
            int xb = xT * 16 + xl + 1;
            float pv[4], vo[4];
            #pragma unroll
            for (int r = 0; r < 4; ++r) {
                int ly = w * 4 + r + 1;
                const uint2* base = (const uint2*)xs;
                uint2 ua = base[(ly + dy0) * 66 + xb + dx0];
                uint2 ub = base[(ly + dy1) * 66 + xb + dx1];
                uint2 uc = base[(ly + 1) * 66 + xb + 1];
                f32x4 acc = (f32x4){0.f, 0.f, 0.f, 0.f};
                acc = __builtin_amdgcn_mfma_f32_16x16x32_bf16(A10, mk8(ua, ub), acc, 0, 0, 0);
                acc = __builtin_amdgcn_mfma_f32_16x16x32_bf16(A11, mk8(uc, uc), acc, 0, 0, 0);
                #pragma unroll
                for (int reg = 0; reg < 4; ++reg) {
                    float val = fmaxf(acc[reg] * inv1[reg] + bs1[reg], 0.f);
                    if (r & 1) {
                        float vm = fmaxf(val, pv[reg]);
                        vo[reg] = fmaxf(vm, __shfl_xor(vm, 1, 64));
                    } else {
                        pv[reg] = val;
                    }
                }
                if ((r & 1) && !(lane & 1)) {
                    int py = h * 16 + w * 2 + (r >> 1);
                    int px = xT * 8 + (xl >> 1);
                    int pos = (py + 1) * 34 + (px + 1);   // bordered
                    unsigned u0 = (unsigned)f2bf(vo[0]) | ((unsigned)f2bf(vo[1]) << 16);
                    unsigned u1 = (unsigned)f2bf(vo[2]) | ((unsigned)f2bf(vo[3]) << 16);
                    unsigned* hp = h1w + pos * 4 + (q & 1) * 2;
                    hp[0] = u0; hp[1] = u1;
                }
            }
        }
    }
    __syncthreads();

    // ======== conv2: 16->32, 32x32, pool -> h2t bordered [18][18][32ic] (split 16+16) ========
    // zero h2t border (concurrent with compute; disjoint addresses)
    if (t < 264) {
        int idx = t >> 1, half = t & 1;
        int y, xx;
        if (idx < 18)      { y = 0;        xx = idx; }
        else if (idx < 36) { y = 17;       xx = idx - 18; }
        else if (idx < 52) { y = idx - 35; xx = 0; }
        else if (idx < 68) { y = idx - 51; xx = 17; }
        else { y = -1; xx = 0; }
        if (y >= 0) {
            uint4 z = {0u, 0u, 0u, 0u};
            int pos = y * 18 + xx;
            *(uint4*)((half ? h2tB : h2tA) + pos * 16) = z;
            *(uint4*)((half ? h2tB : h2tA) + pos * 16 + 8) = z;
        }
    }
    short8 A2[5][2];
    #pragma unroll
    for (int s = 0; s < 5; ++s)
        #pragma unroll
        for (int o = 0; o < 2; ++o)
            A2[s][o] = *(const short8*)(wp2 + (((s * 2 + o) * 64 + lane) << 3));
    int dyA[5], dxA[5];
    #pragma unroll
    for (int s = 0; s < 5; ++s) {
        int tp = s * 2 + (q >> 1); if (tp > 8) tp = 8;
        int d3 = tp / 3;
        dyA[s] = d3 - 1; dxA[s] = tp - d3 * 3 - 1;
    }
    {
        const unsigned short* h1r = (q & 1) ? h1B : h1A;
        f32x4 acc[4][2][2];
        #pragma unroll
        for (int r = 0; r < 4; ++r)
            #pragma unroll
            for (int xT = 0; xT < 2; ++xT)
                #pragma unroll
                for (int o = 0; o < 2; ++o)
                    acc[r][xT][o] = (f32x4){0.f, 0.f, 0.f, 0.f};
        #pragma unroll
        for (int r = 0; r < 4; ++r) {
            int ry = w * 4 + r;
            #pragma unroll
            for (int xT = 0; xT < 2; ++xT) {
                int gxb = xT * 16 + xl;
                #pragma unroll
                for (int s = 0; s < 5; ++s) {
                    int pos = (ry + dyA[s] + 1) * 34 + (gxb + dxA[s] + 1);
                    short8 B = *(const short8*)(h1r + pos * 8);
                    acc[r][xT][0] = __builtin_amdgcn_mfma_f32_16x16x32_bf16(A2[s][0], B, acc[r][xT][0], 0, 0, 0);
                    acc[r][xT][1] = __builtin_amdgcn_mfma_f32_16x16x32_bf16(A2[s][1], B, acc[r][xT][1], 0, 0, 0);
                }
            }
        }
        #pragma unroll
        for (int oT = 0; oT < 2; ++oT)
            #pragma unroll
            for (int rp = 0; rp < 2; ++rp)
                #pragma unroll
                for (int xT = 0; xT < 2; ++xT) {
                    float vo[4];
                    #pragma unroll
                    for (int reg = 0; reg < 4; ++reg) {
                        int oc = oT * 16 + q * 4 + reg;
                        float inv = cst2[oc], bs = cst2[32 + oc];
                        float v0 = fmaxf(acc[rp * 2][xT][oT][reg] * inv + bs, 0.f);
                        float v1 = fmaxf(acc[rp * 2 + 1][xT][oT][reg] * inv + bs, 0.f);
                        float vm = fmaxf(v0, v1);
                        vo[reg] = fmaxf(vm, __shfl_xor(vm, 1, 64));
                    }
                    if (!(lane & 1)) {
                        int py = w * 2 + rp;
                        int px = xT * 8 + (xl >> 1);
                        int pos = (py + 1) * 18 + (px + 1);
                        unsigned u0 = (unsigned)f2bf(vo[0]) | ((unsigned)f2bf(vo[1]) << 16);
                        unsigned u1 = (unsigned)f2bf(vo[2]) | ((unsigned)f2bf(vo[3]) << 16);
                        unsigned* hp = (unsigned*)(oT ? h2tB : h2tA) + pos * 8 + q * 2;
                        hp[0] = u0; hp[1] = u1;
                    }
                }
    }
    __syncthreads();

    // ======== conv3: 32->64, 16x16, pool -> feats [64][68] f32 ========
    {
        int op = w & 1, rg = w >> 1;
        const unsigned short* h2r = (q < 2) ? h2tA : h2tB;
        short8 A3[9][2];
        #pragma unroll
        for (int tap = 0; tap < 9; ++tap)
            #pragma unroll
            for (int tt = 0; tt < 2; ++tt)
                A3[tap][tt] = *(const short8*)(wp3 + (((tap * 4 + op * 2 + tt) * 64 + lane) << 3));
        f32x4 acc[4][2];
        #pragma unroll
        for (int r = 0; r < 4; ++r) {
            acc[r][0] = (f32x4){0.f, 0.f, 0.f, 0.f};
            acc[r][1] = (f32x4){0.f, 0.f, 0.f, 0.f};
        }
        #pragma unroll
        for (int r = 0; r < 4; ++r) {
            int ry = rg * 4 + r + 1;
            #pragma unroll
            for (int tap = 0; tap < 9; ++tap) {
                int pos = (ry + tap / 3 - 1) * 18 + xl + (tap % 3);
                short8 B = *(const short8*)(h2r + pos * 16 + (q & 1) * 8);
                acc[r][0] = __builtin_amdgcn_mfma_f32_16x16x32_bf16(A3[tap][0], B, acc[r][0], 0, 0, 0);
                acc[r][1] = __builtin_amdgcn_mfma_f32_16x16x32_bf16(A3[tap][1], B, acc[r][1], 0, 0, 0);
            }
        }
        #pragma unroll
        for (int tt = 0; tt < 2; ++tt)
            #pragma unroll
            for (int reg = 0; reg < 4; ++reg) {
                int oc = (op * 2 + tt) * 16 + q * 4 + reg;
                float inv = cst3[oc], bs = cst3[64 + oc];
                #pragma unroll
                for (int rp = 0; rp < 2; ++rp) {
                    float v0 = fmaxf(acc[rp * 2][tt][reg] * inv + bs, 0.f);
                    float v1 = fmaxf(acc[rp * 2 + 1][tt][reg] * inv + bs, 0.f);
                    float vm = fmaxf(v0, v1);
                    float vv = fmaxf(vm, __shfl_xor(vm, 1, 64));
                    if (!(lane & 1))
                        feats[oc * 68 + (rg * 2 + rp) * 8 + (xl >> 1)] = vv;
                }
            }
    }
    __syncthreads();

    // ======== head: projection + tanh + analytic quantum map + classifier ========
    if (t < 128) {
        int k = t >> 3, d = t & 7;
        const float4* wrow = (const float4*)(pjwt + (k * 8 + d) * 256);
        float zacc = 0.f;
        #pragma unroll 4
        for (int i = 0; i < 64; ++i) {
            int c4 = (i + k) & 63;
            float4 wv = wrow[c4];
            const float* fp = &feats[(k * 4 + (c4 >> 4)) * 68 + 4 * (c4 & 15)];
            float4 fv = *(const float4*)fp;
            zacc = fmaf(wv.x, fv.x, zacc);
            zacc = fmaf(wv.y, fv.y, zacc);
            zacc = fmaf(wv.z, fv.z, zacc);
            zacc = fmaf(wv.w, fv.w, zacc);
        }
        float z = zacc + pjb[k * 8 + d];
        czs[k * 8 + d] = cosf(0.5f * tanhf(z));
    }
    __syncthreads();
    if (t < 160) {
        int k = t / 10, c = t - (t / 10) * 10;
        float cz[8];
        #pragma unroll
        for (int i = 0; i < 8; ++i) cz[i] = czs[k * 8 + i];
        const float* cwp = cw + c * 576 + k * 36;
        float s = 0.f;
        float pp = 1.f;
        #pragma unroll
        for (int i = 0; i < 8; ++i) { pp *= cz[i]; s = fmaf(pp, cwp[i], s); }
        int cnt = 8;
        #pragma unroll
        for (int i = 0; i < 8; ++i) {
            float p2 = 1.f;
            #pragma unroll
            for (int j = i + 1; j < 8; ++j) { p2 *= cz[j]; s = fmaf(p2, cwp[cnt++], s); }
        }
        partl[k * 10 + c] = s;
    }
    __syncthreads();
    if (t < 10) {
        float s = cbias[t];
        #pragma unroll
        for (int k = 0; k < 16; ++k) s += partl[k * 10 + t];
        out[b * 10 + t] = s;
    }
}

extern "C" void kernel_launch(void* const* d_in, const int* in_sizes, int n_in,
                              void* d_out, int out_size, void* d_ws, size_t ws_size,
                              hipStream_t stream) {
    const float* x     = (const float*)d_in[0];
    const float* c1w   = (const float*)d_in[1];
    const float* c1b   = (const float*)d_in[2];
    const float* b1g   = (const float*)d_in[3];
    const float* b1b   = (const float*)d_in[4];
    const float* b1m   = (const float*)d_in[5];
    const float* b1v   = (const float*)d_in[6];
    const float* c2w   = (const float*)d_in[7];
    const float* c2b   = (const float*)d_in[8];
    const float* b2g   = (const float*)d_in[9];
    const float* b2b   = (const float*)d_in[10];
    const float* b2m   = (const float*)d_in[11];
    const float* b2v   = (const float*)d_in[12];
    const float* c3w   = (const float*)d_in[13];
    const float* c3b   = (const float*)d_in[14];
    const float* b3g   = (const float*)d_in[15];
    const float* b3b   = (const float*)d_in[16];
    const float* b3m   = (const float*)d_in[17];
    const float* b3v   = (const float*)d_in[18];
    const float* pjw   = (const float*)d_in[19];
    const float* pjb   = (const float*)d_in[20];
    const float* cw    = (const float*)d_in[21];
    const float* cbias = (const float*)d_in[22];
    float* outp = (float*)d_out;

    unsigned char* prep = (unsigned char*)d_ws;
    unsigned short* wp2 = (unsigned short*)prep;                       // 5120 bf16
    unsigned short* wp3 = (unsigned short*)(prep + 16384);             // 18432 bf16
    unsigned short* wp1 = (unsigned short*)(prep + 16384 + 36864);     // 1024 bf16
    float* cst2 = (float*)(prep + 16384 + 36864 + 2048);               // 64 f
    float* cst3 = cst2 + 64;                                           // 128 f
    float* cst1 = cst3 + 128;                                          // 32 f
    float* pjwt = (float*)(prep + 16384 + 36864 + 2048 + 1024);        // 32768 f

    k_prep<<<225, 256, 0, stream>>>(c2w, c3w, b2g, b2b, b2m, b2v, c2b,
                                    b3g, b3b, b3m, b3v, c3b,
                                    c1w, b1g, b1b, b1m, b1v, c1b, pjw,
                                    wp2, wp3, wp1, cst2, cst3, cst1, pjwt);
    k_fused<<<512, 512, 0, stream>>>(x, wp1, cst1, wp2, cst2, wp3, cst3,
                                     pjwt, pjb, cw, cbias, outp);
}